// Round 2
// baseline (9396.534 us; speedup 1.0000x reference)
//
#include <hip/hip_runtime.h>

#define Nn 16384
#define Ee 262144
#define Dd 128
#define DEe 64
#define Hh 256
#define KK 16
#define NSPLIT 16
#define TT 128      /* targets per block */
#define STILE 256   /* source tile */
#define KCH 32      /* k chunk */
#define SWEEP (Nn / NSPLIT) /* 1024 sources per block */
#define PA 129      /* xt pitch */
#define PB 257      /* xs pitch */
#define PD 66       /* dtile pitch */

// edge_index access: mode=1 -> int32 layout, mode=0 -> int64 (low words at even positions)
__device__ __forceinline__ int ld_src(const int* ei, int e, int mode) {
  return mode ? ei[e] : ei[2 * e];
}
__device__ __forceinline__ int ld_dst(const int* ei, int e, int mode) {
  return mode ? ei[Ee + e] : ei[2 * Ee + 2 * e];
}

__global__ void k_detect(const int* __restrict__ ei, int* __restrict__ flag) {
  if (blockIdx.x == 0 && threadIdx.x == 0) {
    int any = 0;
    for (int i = 0; i < 64; ++i) any |= ei[2 * i + 1];
    *flag = (any != 0) ? 1 : 0;  // any odd word nonzero -> int32 layout
  }
}

__global__ void k_hist(const int* __restrict__ ei, const int* __restrict__ mode_p,
                       int* __restrict__ hist) {
  int e = blockIdx.x * 256 + threadIdx.x;
  int mode = *mode_p;
  atomicAdd(&hist[ld_dst(ei, e, mode)], 1);
}

__global__ void k_scan(const int* __restrict__ hist, int* __restrict__ cursor) {
  __shared__ int part[256];
  __shared__ int partx[256];
  int t = threadIdx.x;
  int base = t * (Nn / 256);
  int s = 0;
  for (int i = 0; i < Nn / 256; ++i) s += hist[base + i];
  part[t] = s;
  __syncthreads();
  if (t == 0) {
    int run = 0;
    for (int i = 0; i < 256; ++i) { partx[i] = run; run += part[i]; }
  }
  __syncthreads();
  int run = partx[t];
  for (int i = 0; i < Nn / 256; ++i) { int v = hist[base + i]; cursor[base + i] = run; run += v; }
}

__global__ void k_scatter(const int* __restrict__ ei, const int* __restrict__ mode_p,
                          int* __restrict__ cursor, int* __restrict__ perm,
                          int* __restrict__ dstS) {
  int e = blockIdx.x * 256 + threadIdx.x;
  int mode = *mode_p;
  int d = ld_dst(ei, e, mode);
  int pos = atomicAdd(&cursor[d], 1);
  perm[pos] = e;
  dstS[pos] = d;
}

__global__ void k_sq(const float* __restrict__ x, float* __restrict__ sq) {
  int n = blockIdx.x * 256 + threadIdx.x;
  const float4* p = (const float4*)(x + (size_t)n * Dd);
  float acc = 0.f;
#pragma unroll
  for (int i = 0; i < Dd / 4; ++i) {
    float4 v = p[i];
    acc += v.x * v.x + v.y * v.y + v.z * v.z + v.w * v.w;
  }
  sq[n] = acc;
}

// ---------------- kNN: 128 targets/block, 16-way split, 16x8 reg tiles, all-thread scan ----
__global__ __launch_bounds__(256, 2) void k_knn_part(const float* __restrict__ x,
                                                     const float* __restrict__ sq,
                                                     float* __restrict__ part_d,
                                                     int* __restrict__ part_i) {
  __shared__ float smA[KCH * PA];   // xt chunk [k][t], pitch 129
  __shared__ float smB[TT * PD];    // xs chunk [k][s] pitch 257 (8224f) / dtile [t][64] pitch 66 / merge lists
  __shared__ float sqs_l[STILE];
  int tid = threadIdx.x;
  int tileT = blockIdx.x >> 4;
  int split = blockIdx.x & 15;
  int tb = tileT * TT;
  int ty = tid >> 5;   // 0..7 : target group of 16
  int tx = tid & 31;   // 0..31: source group (two float4 at stride 128)
  int kf = tid & 7;
  int t0 = tid >> 3;
  // scan role: target tg = tid>>1 (0..127), parity slice sl = tid&1
  int tg = tid >> 1, sl = tid & 1;
  float sqi = sq[tb + tg];

  float bd[KK];
  int bi[KK];
#pragma unroll
  for (int p2 = 0; p2 < KK; ++p2) { bd[p2] = 3.0e38f; bi[p2] = 0x7fffffff; }

#pragma unroll 1
  for (int st = 0; st < SWEEP / STILE; ++st) {  // 4 source tiles
    int sb = split * SWEEP + st * STILE;
    float acc[128];
#pragma unroll
    for (int i = 0; i < 128; ++i) acc[i] = 0.f;

#pragma unroll 1
    for (int kc = 0; kc < Dd / KCH; ++kc) {  // 4 k-chunks
      __syncthreads();  // prior use of smA/smB done
      // stage xt chunk: [32k][128t] transposed, ~conflict-free writes
#pragma unroll
      for (int m = 0; m < 4; ++m) {
        int t = t0 + m * 32;
        float4 g = *(const float4*)&x[(size_t)(tb + t) * Dd + kc * KCH + kf * 4];
        smA[(kf * 4 + 0) * PA + t] = g.x;
        smA[(kf * 4 + 1) * PA + t] = g.y;
        smA[(kf * 4 + 2) * PA + t] = g.z;
        smA[(kf * 4 + 3) * PA + t] = g.w;
      }
      // stage xs chunk: [32k][256s]
#pragma unroll
      for (int m = 0; m < 8; ++m) {
        int s = t0 + m * 32;
        float4 g = *(const float4*)&x[(size_t)(sb + s) * Dd + kc * KCH + kf * 4];
        smB[(kf * 4 + 0) * PB + s] = g.x;
        smB[(kf * 4 + 1) * PB + s] = g.y;
        smB[(kf * 4 + 2) * PB + s] = g.z;
        smB[(kf * 4 + 3) * PB + s] = g.w;
      }
      if (kc == 0) sqs_l[tid] = sq[sb + tid];
      __syncthreads();
#pragma unroll 2
      for (int k = 0; k < KCH; ++k) {
        const float* ap = &smA[k * PA + ty * 16];
        float4 a0 = *(const float4*)(ap);
        float4 a1 = *(const float4*)(ap + 4);
        float4 a2 = *(const float4*)(ap + 8);
        float4 a3 = *(const float4*)(ap + 12);
        const float* bp = &smB[k * PB + tx * 4];
        float4 b0 = *(const float4*)(bp);
        float4 b1 = *(const float4*)(bp + 128);
        float av[16] = {a0.x, a0.y, a0.z, a0.w, a1.x, a1.y, a1.z, a1.w,
                        a2.x, a2.y, a2.z, a2.w, a3.x, a3.y, a3.z, a3.w};
        float bv[8] = {b0.x, b0.y, b0.z, b0.w, b1.x, b1.y, b1.z, b1.w};
#pragma unroll
        for (int r = 0; r < 16; ++r)
#pragma unroll
          for (int c = 0; c < 8; ++c) acc[r * 8 + c] = fmaf(av[r], bv[c], acc[r * 8 + c]);
      }
    }

    // write+scan distances in 64-source quarters (dtile aliases xs buffer)
#pragma unroll
    for (int q = 0; q < 4; ++q) {
      __syncthreads();  // previous quarter scanned / compute reads done
      if ((tx >> 4) == (q & 1)) {
        int cl = (tx & 15) * 4;
        int h = (q >> 1) * 4;
#pragma unroll
        for (int r = 0; r < 16; ++r) {
          float4 o;
          o.x = acc[r * 8 + h + 0];
          o.y = acc[r * 8 + h + 1];
          o.z = acc[r * 8 + h + 2];
          o.w = acc[r * 8 + h + 3];
          *(float4*)&smB[(ty * 16 + r) * PD + cl] = o;
        }
      }
      __syncthreads();
      const float* drow = &smB[tg * PD];
      const float* sqrow = &sqs_l[q * 64];
#pragma unroll 1
      for (int j = 0; j < 32; ++j) {
        int col = sl + 2 * j;  // ascending within thread -> tie keeps lower index
        float dot = drow[col];
        float d = fmaf(-2.f, dot, sqi) + sqrow[col];
        int gidx = sb + q * 64 + col;
        if (d < bd[KK - 1]) {
#pragma unroll
          for (int p = KK - 1; p >= 1; --p) {
            bool shift = d < bd[p - 1];
            bool here = (!shift) && (d < bd[p]);
            float nb = shift ? bd[p - 1] : (here ? d : bd[p]);
            int ni = shift ? bi[p - 1] : (here ? gidx : bi[p]);
            bd[p] = nb;
            bi[p] = ni;
          }
          if (d < bd[0]) { bd[0] = d; bi[0] = gidx; }
        }
      }
    }
  }

  // block-end: merge the two parity lists per target -> sorted 16 per (target, split)
  __syncthreads();
  int* smBi = (int*)smB;
#pragma unroll
  for (int o = 0; o < KK; ++o) {
    smB[tid * KK + o] = bd[o];
    smBi[4096 + tid * KK + o] = bi[o];
  }
  __syncthreads();
  if (tid < TT) {
    const float* la = &smB[(2 * tid) * KK];
    const float* lb = &smB[(2 * tid + 1) * KK];
    const int* ia = &smBi[4096 + (2 * tid) * KK];
    const int* ib = &smBi[4096 + (2 * tid + 1) * KK];
    int pa = 0, pb = 0;
    size_t base = ((size_t)(tb + tid) * NSPLIT + split) * KK;
#pragma unroll
    for (int o = 0; o < KK; ++o) {
      float da = la[pa], db = lb[pb];
      int iaa = ia[pa], ibb = ib[pb];
      bool pick = (da < db) || (da == db && iaa < ibb);
      part_d[base + o] = pick ? da : db;
      part_i[base + o] = pick ? iaa : ibb;
      pa += pick ? 1 : 0;
      pb += pick ? 0 : 1;
    }
  }
}

__global__ void k_knn_merge(const float* __restrict__ part_d, const int* __restrict__ part_i,
                            int* __restrict__ knn_src) {
  int n = blockIdx.x * 256 + threadIdx.x;
  const float* pd = part_d + (size_t)n * NSPLIT * KK;
  const int* pi = part_i + (size_t)n * NSPLIT * KK;
  int pos[NSPLIT];
#pragma unroll
  for (int l = 0; l < NSPLIT; ++l) pos[l] = 0;
  for (int o = 0; o < KK; ++o) {
    float bestd = 3.3e38f;
    int besti = 0x7fffffff;
    int bestl = 0;
#pragma unroll
    for (int l = 0; l < NSPLIT; ++l) {
      if (pos[l] < KK) {
        float dd = pd[l * KK + pos[l]];
        int ii = pi[l * KK + pos[l]];
        if (dd < bestd || (dd == bestd && ii < besti)) { bestd = dd; besti = ii; bestl = l; }
      }
    }
    knn_src[n * KK + o] = besti;
#pragma unroll
    for (int l = 0; l < NSPLIT; ++l) pos[l] += (l == bestl) ? 1 : 0;
  }
}

// ---------------- fused 2-layer MLP cores (32 rows/block, H=256, out=128) ----------------
// smA: inT [k][32] (k<indim) during L1, then hidden [32 rows][pitch 260] fp32
// smB: weight K-chunk staging (2048 floats)
__device__ __forceinline__ void mlp_l1(int tid, int indim, const float* __restrict__ W1,
                                       const float* __restrict__ b1, float* smA, float* smB) {
  int rg = tid >> 5, cg = tid & 31;  // rows rg*4..+4, cols cg*8..+8
  float acc[32];
#pragma unroll
  for (int i = 0; i < 32; ++i) acc[i] = 0.f;
  for (int kc = 0; kc < indim / 8; ++kc) {
    const float* W1g = W1 + (size_t)kc * 8 * Hh;
    *(float4*)&smB[tid * 4] = *(const float4*)&W1g[tid * 4];
    *(float4*)&smB[1024 + tid * 4] = *(const float4*)&W1g[1024 + tid * 4];
    __syncthreads();
#pragma unroll
    for (int k = 0; k < 8; ++k) {
      int kk = kc * 8 + k;
      float4 a0 = *(const float4*)&smA[kk * 32 + rg * 4];
      float4 b0 = *(const float4*)&smB[k * Hh + cg * 8];
      float4 b1v = *(const float4*)&smB[k * Hh + cg * 8 + 4];
      float av[4] = {a0.x, a0.y, a0.z, a0.w};
      float bv[8] = {b0.x, b0.y, b0.z, b0.w, b1v.x, b1v.y, b1v.z, b1v.w};
#pragma unroll
      for (int rr = 0; rr < 4; ++rr)
#pragma unroll
        for (int cc = 0; cc < 8; ++cc) acc[rr * 8 + cc] += av[rr] * bv[cc];
    }
    __syncthreads();
  }
  float4 bb0 = *(const float4*)&b1[cg * 8];
  float4 bb1 = *(const float4*)&b1[cg * 8 + 4];
  float bs[8] = {bb0.x, bb0.y, bb0.z, bb0.w, bb1.x, bb1.y, bb1.z, bb1.w};
#pragma unroll
  for (int rr = 0; rr < 4; ++rr) {
    int row = rg * 4 + rr;
    float4 h0, h1;
    h0.x = fmaxf(acc[rr * 8 + 0] + bs[0], 0.f);
    h0.y = fmaxf(acc[rr * 8 + 1] + bs[1], 0.f);
    h0.z = fmaxf(acc[rr * 8 + 2] + bs[2], 0.f);
    h0.w = fmaxf(acc[rr * 8 + 3] + bs[3], 0.f);
    h1.x = fmaxf(acc[rr * 8 + 4] + bs[4], 0.f);
    h1.y = fmaxf(acc[rr * 8 + 5] + bs[5], 0.f);
    h1.z = fmaxf(acc[rr * 8 + 6] + bs[6], 0.f);
    h1.w = fmaxf(acc[rr * 8 + 7] + bs[7], 0.f);
    *(float4*)&smA[row * 260 + cg * 8] = h0;
    *(float4*)&smA[row * 260 + cg * 8 + 4] = h1;
  }
  __syncthreads();
}

__device__ __forceinline__ void mlp_l2(int tid, const float* __restrict__ W2,
                                       const float* smA, float* smB, float acc2[16]) {
  int rg2 = tid >> 5, cg2 = tid & 31;  // rows rg2*4..+4, cols cg2*4..+4
#pragma unroll
  for (int i = 0; i < 16; ++i) acc2[i] = 0.f;
  for (int kc = 0; kc < Hh / 16; ++kc) {
    const float* W2g = W2 + (size_t)kc * 16 * Dd;
    *(float4*)&smB[tid * 4] = *(const float4*)&W2g[tid * 4];
    *(float4*)&smB[1024 + tid * 4] = *(const float4*)&W2g[1024 + tid * 4];
    __syncthreads();
#pragma unroll
    for (int k = 0; k < 16; ++k) {
      int kk = kc * 16 + k;
      float4 b0 = *(const float4*)&smB[k * Dd + cg2 * 4];
#pragma unroll
      for (int rr = 0; rr < 4; ++rr) {
        float a = smA[(rg2 * 4 + rr) * 260 + kk];
        acc2[rr * 4 + 0] += a * b0.x;
        acc2[rr * 4 + 1] += a * b0.y;
        acc2[rr * 4 + 2] += a * b0.z;
        acc2[rr * 4 + 3] += a * b0.w;
      }
    }
    __syncthreads();
  }
}

// ---------------- static message MLP + grouped scatter-add ----------------
__global__ __launch_bounds__(256, 3) void k_static_msg(
    const float* __restrict__ xs, const float* __restrict__ ea, const int* __restrict__ ei,
    const int* __restrict__ mode_p, const int* __restrict__ perm, const int* __restrict__ dstS,
    const float* __restrict__ W1, const float* __restrict__ b1, const float* __restrict__ W2,
    const float* __restrict__ b2, float* __restrict__ agg) {
  __shared__ float smA[32 * 260];
  __shared__ float smB[2048];
  __shared__ int dstLoc[32];
  int tid = threadIdx.x;
  int pb = blockIdx.x * 32;
  int mode = *mode_p;
  int r = tid & 31, q = tid >> 5;
  int p = pb + r;
  int e = perm[p];
  int ds = dstS[p];
  int sr = ld_src(ei, e, mode);
  if (q == 0) dstLoc[r] = ds;
  const float* eap = ea + (size_t)e * DEe;
#pragma unroll
  for (int m = 0; m < 2; ++m) {
    int k0 = q * 8 + m * 4;
    float4 v = *(const float4*)&eap[k0];
    smA[(k0 + 0) * 32 + r] = v.x;
    smA[(k0 + 1) * 32 + r] = v.y;
    smA[(k0 + 2) * 32 + r] = v.z;
    smA[(k0 + 3) * 32 + r] = v.w;
  }
  const float* xsp = xs + (size_t)sr * Dd;
  const float* xdp = xs + (size_t)ds * Dd;
#pragma unroll
  for (int m = 0; m < 4; ++m) {
    int f0 = q * 16 + m * 4;
    float4 a = *(const float4*)&xsp[f0];
    float4 b = *(const float4*)&xdp[f0];
    smA[(DEe + f0 + 0) * 32 + r] = a.x - b.x;
    smA[(DEe + f0 + 1) * 32 + r] = a.y - b.y;
    smA[(DEe + f0 + 2) * 32 + r] = a.z - b.z;
    smA[(DEe + f0 + 3) * 32 + r] = a.w - b.w;
  }
  __syncthreads();
  mlp_l1(tid, DEe + Dd, W1, b1, smA, smB);
  float acc2[16];
  mlp_l2(tid, W2, smA, smB, acc2);
  int rg2 = tid >> 5, cg2 = tid & 31;
  float4 ob = *(const float4*)&b2[cg2 * 4];
#pragma unroll
  for (int rr = 0; rr < 4; ++rr) {
    int row = rg2 * 4 + rr;
    float4 o;
    o.x = fmaxf(acc2[rr * 4 + 0] + ob.x, 0.f);
    o.y = fmaxf(acc2[rr * 4 + 1] + ob.y, 0.f);
    o.z = fmaxf(acc2[rr * 4 + 2] + ob.z, 0.f);
    o.w = fmaxf(acc2[rr * 4 + 3] + ob.w, 0.f);
    *(float4*)&smA[row * 132 + cg2 * 4] = o;  // outT [32][132]
  }
  __syncthreads();
  int col = tid & 127, half = tid >> 7;
  int r0 = half * 16;
  float run = smA[r0 * 132 + col];
  int prevd = dstLoc[r0];
  for (int rr = 1; rr < 16; ++rr) {
    int row = r0 + rr;
    int dd2 = dstLoc[row];
    float v = smA[row * 132 + col];
    if (dd2 != prevd) {
      atomicAdd(&agg[(size_t)prevd * Dd + col], run);
      run = v;
      prevd = dd2;
    } else {
      run += v;
    }
  }
  atomicAdd(&agg[(size_t)prevd * Dd + col], run);
}

// ---------------- dynamic (kNN) message MLP, atomic-free aggregation ----------------
__global__ __launch_bounds__(256, 3) void k_dyn_msg(
    const float* __restrict__ xd, const int* __restrict__ knn, const float* __restrict__ W1,
    const float* __restrict__ b1, const float* __restrict__ W2, const float* __restrict__ b2,
    float* __restrict__ agg) {
  __shared__ float smA[32 * 260];
  __shared__ float smB[2048];
  __shared__ float pbuf[4 * 128];
  int tid = threadIdx.x;
  int nb2 = blockIdx.x * 2;  // 2 targets, 16 messages each = 32 rows
  int r = tid & 31, q = tid >> 5;
  int tgt = nb2 + (r >> 4);
  int nj = knn[tgt * KK + (r & 15)];
  const float* xip = xd + (size_t)tgt * Dd;
  const float* xjp = xd + (size_t)nj * Dd;
#pragma unroll
  for (int m = 0; m < 4; ++m) {
    int f0 = q * 16 + m * 4;
    float4 v = *(const float4*)&xip[f0];
    float4 a = *(const float4*)&xjp[f0];
    smA[(f0 + 0) * 32 + r] = v.x;
    smA[(f0 + 1) * 32 + r] = v.y;
    smA[(f0 + 2) * 32 + r] = v.z;
    smA[(f0 + 3) * 32 + r] = v.w;
    smA[(Dd + f0 + 0) * 32 + r] = a.x - v.x;
    smA[(Dd + f0 + 1) * 32 + r] = a.y - v.y;
    smA[(Dd + f0 + 2) * 32 + r] = a.z - v.z;
    smA[(Dd + f0 + 3) * 32 + r] = a.w - v.w;
  }
  __syncthreads();
  mlp_l1(tid, 2 * Dd, W1, b1, smA, smB);
  float acc2[16];
  mlp_l2(tid, W2, smA, smB, acc2);
  int rg2 = tid >> 5, cg2 = tid & 31;
  float4 ob = *(const float4*)&b2[cg2 * 4];
  float s0 = 0.f, s1 = 0.f, s2 = 0.f, s3 = 0.f;
#pragma unroll
  for (int rr = 0; rr < 4; ++rr) {
    s0 += fmaxf(acc2[rr * 4 + 0] + ob.x, 0.f);
    s1 += fmaxf(acc2[rr * 4 + 1] + ob.y, 0.f);
    s2 += fmaxf(acc2[rr * 4 + 2] + ob.z, 0.f);
    s3 += fmaxf(acc2[rr * 4 + 3] + ob.w, 0.f);
  }
  s0 += __shfl_xor(s0, 32);
  s1 += __shfl_xor(s1, 32);
  s2 += __shfl_xor(s2, 32);
  s3 += __shfl_xor(s3, 32);
  if ((rg2 & 1) == 0) {
    float4 o;
    o.x = s0; o.y = s1; o.z = s2; o.w = s3;
    *(float4*)&pbuf[(rg2 >> 1) * 128 + cg2 * 4] = o;
  }
  __syncthreads();
  int c = tid & 127, g = tid >> 7;
  float v = pbuf[(g * 2) * 128 + c] + pbuf[(g * 2 + 1) * 128 + c];
  agg[(size_t)(nb2 + g) * Dd + c] = v;
}

// ---------------- generic node MLP (update / fuse) ----------------
__global__ __launch_bounds__(256, 3) void k_node_mlp2(
    const float* __restrict__ in1, const float* __restrict__ in2, int indim,
    const float* __restrict__ W1, const float* __restrict__ b1, const float* __restrict__ W2,
    const float* __restrict__ b2, float* __restrict__ out) {
  __shared__ float smA[32 * 260];
  __shared__ float smB[2048];
  int tid = threadIdx.x;
  int nb = blockIdx.x * 32;
  int r = tid & 31, q = tid >> 5;
  for (int pass = 0; pass < indim / 32; ++pass) {
    int k0 = pass * 32 + q * 4;
    float4 v;
    if (k0 < Dd)
      v = *(const float4*)&in1[(size_t)(nb + r) * Dd + k0];
    else
      v = *(const float4*)&in2[(size_t)(nb + r) * Dd + (k0 - Dd)];
    smA[(k0 + 0) * 32 + r] = v.x;
    smA[(k0 + 1) * 32 + r] = v.y;
    smA[(k0 + 2) * 32 + r] = v.z;
    smA[(k0 + 3) * 32 + r] = v.w;
  }
  __syncthreads();
  mlp_l1(tid, indim, W1, b1, smA, smB);
  float acc2[16];
  mlp_l2(tid, W2, smA, smB, acc2);
  int rg2 = tid >> 5, cg2 = tid & 31;
  float4 ob = *(const float4*)&b2[cg2 * 4];
#pragma unroll
  for (int rr = 0; rr < 4; ++rr) {
    float4 o;
    o.x = fmaxf(acc2[rr * 4 + 0] + ob.x, 0.f);
    o.y = fmaxf(acc2[rr * 4 + 1] + ob.y, 0.f);
    o.z = fmaxf(acc2[rr * 4 + 2] + ob.z, 0.f);
    o.w = fmaxf(acc2[rr * 4 + 3] + ob.w, 0.f);
    *(float4*)&out[(size_t)(nb + rg2 * 4 + rr) * Dd + cg2 * 4] = o;
  }
}

// ---------------- edge refiner: ea = relu(ea @ rW + rb), 64->64 ----------------
__global__ __launch_bounds__(256) void k_refine(const float* __restrict__ ein,
                                                const float* __restrict__ rW,
                                                const float* __restrict__ rb,
                                                float* __restrict__ eout) {
  __shared__ float lea[16 * 64];
  __shared__ float ldsW[64 * 64];
  int tid = threadIdx.x;
  int eb = blockIdx.x * 16;
  *(float4*)&lea[tid * 4] = *(const float4*)&ein[(size_t)eb * DEe + tid * 4];
#pragma unroll
  for (int m = 0; m < 4; ++m) {
    int i4 = tid + m * 256;
    *(float4*)&ldsW[i4 * 4] = *(const float4*)&rW[i4 * 4];
  }
  __syncthreads();
  int j = tid & 63, eg = tid >> 6;  // thread: output col j for edges eg, eg+4, eg+8, eg+12
  float bias = rb[j];
  float acc0 = 0.f, acc1 = 0.f, acc2 = 0.f, acc3 = 0.f;
#pragma unroll 8
  for (int k = 0; k < 64; ++k) {
    float w = ldsW[k * 64 + j];
    acc0 += lea[(eg + 0) * 64 + k] * w;
    acc1 += lea[(eg + 4) * 64 + k] * w;
    acc2 += lea[(eg + 8) * 64 + k] * w;
    acc3 += lea[(eg + 12) * 64 + k] * w;
  }
  eout[(size_t)(eb + eg + 0) * DEe + j] = fmaxf(acc0 + bias, 0.f);
  eout[(size_t)(eb + eg + 4) * DEe + j] = fmaxf(acc1 + bias, 0.f);
  eout[(size_t)(eb + eg + 8) * DEe + j] = fmaxf(acc2 + bias, 0.f);
  eout[(size_t)(eb + eg + 12) * DEe + j] = fmaxf(acc3 + bias, 0.f);
}

extern "C" void kernel_launch(void* const* d_in, const int* in_sizes, int n_in, void* d_out,
                              int out_size, void* d_ws, size_t ws_size, hipStream_t stream) {
  (void)in_sizes; (void)n_in; (void)out_size; (void)ws_size;
  const float* x = (const float*)d_in[0];
  const float* edge_attr = (const float*)d_in[1];
  const float* sW1 = (const float*)d_in[2];
  const float* sb1 = (const float*)d_in[3];
  const float* sW2 = (const float*)d_in[4];
  const float* sb2 = (const float*)d_in[5];
  const float* uW1 = (const float*)d_in[6];
  const float* ub1 = (const float*)d_in[7];
  const float* uW2 = (const float*)d_in[8];
  const float* ub2 = (const float*)d_in[9];
  const float* rW = (const float*)d_in[10];
  const float* rb = (const float*)d_in[11];
  const float* dW1 = (const float*)d_in[12];
  const float* db1 = (const float*)d_in[13];
  const float* dW2 = (const float*)d_in[14];
  const float* db2 = (const float*)d_in[15];
  const float* dUW1 = (const float*)d_in[16];
  const float* dUb1 = (const float*)d_in[17];
  const float* dUW2 = (const float*)d_in[18];
  const float* dUb2 = (const float*)d_in[19];
  const float* fW1 = (const float*)d_in[20];
  const float* fb1 = (const float*)d_in[21];
  const float* fW2 = (const float*)d_in[22];
  const float* fb2 = (const float*)d_in[23];
  const int* ei = (const int*)d_in[24];
  float* out = (float*)d_out;

  float* wsf = (float*)d_ws;
  size_t off = 0;
  float* ea_ws = wsf + off; off += (size_t)Ee * DEe;
  float* xs_ws = wsf + off; off += (size_t)Nn * Dd;
  float* xd_ws = wsf + off; off += (size_t)Nn * Dd;
  float* agg = wsf + off;   off += (size_t)Nn * Dd;
  float* sq = wsf + off;    off += Nn;
  int* knn_src = (int*)(wsf + off); off += (size_t)Nn * KK;
  int* hist = (int*)(wsf + off);   off += Nn;
  int* cursor = (int*)(wsf + off); off += Nn;
  int* perm = (int*)(wsf + off);   off += Ee;
  int* dstS = (int*)(wsf + off);   off += Ee;
  int* modep = (int*)(wsf + off);  off += 1;
  // kNN partial lists overlap ea_ws: edge_attr refinement is dead before the dynamic branch runs
  float* part_d = ea_ws;
  int* part_i = (int*)(ea_ws + (size_t)Nn * NSPLIT * KK);

  // edge_index layout probe + counting sort by dst (CSR ordering)
  k_detect<<<1, 64, 0, stream>>>(ei, modep);
  hipMemsetAsync(hist, 0, Nn * sizeof(int), stream);
  k_hist<<<Ee / 256, 256, 0, stream>>>(ei, modep, hist);
  k_scan<<<1, 256, 0, stream>>>(hist, cursor);
  k_scatter<<<Ee / 256, 256, 0, stream>>>(ei, modep, cursor, perm, dstS);

  // ---- static branch: 3 convs + 2 refiners ----
  const float* xs_cur = x;
  const float* ea_cur = edge_attr;
  for (int i = 0; i < 3; ++i) {
    hipMemsetAsync(agg, 0, (size_t)Nn * Dd * sizeof(float), stream);
    k_static_msg<<<Ee / 32, 256, 0, stream>>>(
        xs_cur, ea_cur, ei, modep, perm, dstS, sW1 + (size_t)i * (DEe + Dd) * Hh,
        sb1 + (size_t)i * Hh, sW2 + (size_t)i * Hh * Dd, sb2 + (size_t)i * Dd, agg);
    k_node_mlp2<<<Nn / 32, 256, 0, stream>>>(
        agg, (const float*)nullptr, Dd, uW1 + (size_t)i * Dd * Hh, ub1 + (size_t)i * Hh,
        uW2 + (size_t)i * Hh * Dd, ub2 + (size_t)i * Dd, xs_ws);
    xs_cur = xs_ws;
    if (i < 2) {
      k_refine<<<Ee / 16, 256, 0, stream>>>(ea_cur, rW + (size_t)i * DEe * DEe,
                                            rb + (size_t)i * DEe, ea_ws);
      ea_cur = ea_ws;
    }
  }

  // ---- dynamic branch: 2 kNN convs ----
  const float* xd_cur = x;
  for (int i = 0; i < 2; ++i) {
    k_sq<<<Nn / 256, 256, 0, stream>>>(xd_cur, sq);
    k_knn_part<<<(Nn / TT) * NSPLIT, 256, 0, stream>>>(xd_cur, sq, part_d, part_i);
    k_knn_merge<<<Nn / 256, 256, 0, stream>>>(part_d, part_i, knn_src);
    k_dyn_msg<<<Nn / 2, 256, 0, stream>>>(
        xd_cur, knn_src, dW1 + (size_t)i * 2 * Dd * Hh, db1 + (size_t)i * Hh,
        dW2 + (size_t)i * Hh * Dd, db2 + (size_t)i * Dd, agg);
    k_node_mlp2<<<Nn / 32, 256, 0, stream>>>(
        agg, (const float*)nullptr, Dd, dUW1 + (size_t)i * Dd * Hh, dUb1 + (size_t)i * Hh,
        dUW2 + (size_t)i * Hh * Dd, dUb2 + (size_t)i * Dd, xd_ws);
    xd_cur = xd_ws;
  }

  // ---- fuse MLP: concat(xs, xd) 256 -> 256 -> 128 ----
  k_node_mlp2<<<Nn / 32, 256, 0, stream>>>(xs_ws, xd_ws, 2 * Dd, fW1, fb1, fW2, fb2, out);
}

// Round 3
// 6521.482 us; speedup vs baseline: 1.4409x; 1.4409x over previous
//
#include <hip/hip_runtime.h>

#define Nn 16384
#define Ee 262144
#define Dd 128
#define DEe 64
#define Hh 256
#define KK 16
#define NSPLIT 16
#define TT 128      /* targets per block */
#define STILE 128   /* source tile */
#define KCH 32      /* k chunk */
#define SWEEP (Nn / NSPLIT) /* 1024 sources per split */
#define PA 132      /* A chunk pitch */
#define PB 132      /* B chunk pitch */
#define PDt 68      /* dtile pitch */

// edge_index access: mode=1 -> int32 layout, mode=0 -> int64 (low words at even positions)
__device__ __forceinline__ int ld_src(const int* ei, int e, int mode) {
  return mode ? ei[e] : ei[2 * e];
}
__device__ __forceinline__ int ld_dst(const int* ei, int e, int mode) {
  return mode ? ei[Ee + e] : ei[2 * Ee + 2 * e];
}

__global__ void k_detect(const int* __restrict__ ei, int* __restrict__ flag) {
  if (blockIdx.x == 0 && threadIdx.x == 0) {
    int any = 0;
    for (int i = 0; i < 64; ++i) any |= ei[2 * i + 1];
    *flag = (any != 0) ? 1 : 0;  // any odd word nonzero -> int32 layout
  }
}

__global__ void k_hist(const int* __restrict__ ei, const int* __restrict__ mode_p,
                       int* __restrict__ hist) {
  int e = blockIdx.x * 256 + threadIdx.x;
  int mode = *mode_p;
  atomicAdd(&hist[ld_dst(ei, e, mode)], 1);
}

__global__ void k_scan(const int* __restrict__ hist, int* __restrict__ cursor) {
  __shared__ int part[256];
  __shared__ int partx[256];
  int t = threadIdx.x;
  int base = t * (Nn / 256);
  int s = 0;
  for (int i = 0; i < Nn / 256; ++i) s += hist[base + i];
  part[t] = s;
  __syncthreads();
  if (t == 0) {
    int run = 0;
    for (int i = 0; i < 256; ++i) { partx[i] = run; run += part[i]; }
  }
  __syncthreads();
  int run = partx[t];
  for (int i = 0; i < Nn / 256; ++i) { int v = hist[base + i]; cursor[base + i] = run; run += v; }
}

__global__ void k_scatter(const int* __restrict__ ei, const int* __restrict__ mode_p,
                          int* __restrict__ cursor, int* __restrict__ perm,
                          int* __restrict__ dstS) {
  int e = blockIdx.x * 256 + threadIdx.x;
  int mode = *mode_p;
  int d = ld_dst(ei, e, mode);
  int pos = atomicAdd(&cursor[d], 1);
  perm[pos] = e;
  dstS[pos] = d;
}

__global__ void k_sq(const float* __restrict__ x, float* __restrict__ sq) {
  int n = blockIdx.x * 256 + threadIdx.x;
  const float4* p = (const float4*)(x + (size_t)n * Dd);
  float acc = 0.f;
#pragma unroll
  for (int i = 0; i < Dd / 4; ++i) {
    float4 v = p[i];
    acc += v.x * v.x + v.y * v.y + v.z * v.z + v.w * v.w;
  }
  sq[n] = acc;
}

// ---- kNN: 128 targets x 128 sources per block, 8x8 reg tiles (acc[64], no spill) ----
__global__ __launch_bounds__(256, 3) void k_knn_part(const float* __restrict__ x,
                                                     const float* __restrict__ sq,
                                                     float* __restrict__ part_d,
                                                     int* __restrict__ part_i) {
  __shared__ float smU[TT * PDt];  // 8704 floats: A+B staging (8448) / dtile / merge lists
  __shared__ float sqs_l[STILE];
  float* smA = smU;             // [KCH][PA]
  float* smB = smU + KCH * PA;  // [KCH][PB]
  int tid = threadIdx.x;
  int tileT = blockIdx.x >> 4;
  int split = blockIdx.x & 15;
  int tb = tileT * TT;
  int ty = tid >> 4, tx = tid & 15;  // 8x8 tile: rows ty*8.., cols tx*8..
  int kf = tid & 7, t0 = tid >> 3;   // staging roles
  int tg = tid >> 1, sl = tid & 1;   // scan roles: target row, parity slice
  float sqi = sq[tb + tg];

  float bd[KK];
  int bi[KK];
#pragma unroll
  for (int p2 = 0; p2 < KK; ++p2) { bd[p2] = 3.0e38f; bi[p2] = 0x7fffffff; }

#pragma unroll 1
  for (int st = 0; st < SWEEP / STILE; ++st) {  // 8 source tiles
    int sb = split * SWEEP + st * STILE;
    float acc[64];
#pragma unroll
    for (int i = 0; i < 64; ++i) acc[i] = 0.f;

#pragma unroll 1
    for (int kc = 0; kc < Dd / KCH; ++kc) {  // 4 k-chunks
      __syncthreads();  // prior use of smU (scan/merge/compute) done
      // stage A chunk [32k][128t]
#pragma unroll
      for (int m = 0; m < 4; ++m) {
        int t = t0 + m * 32;
        float4 g = *(const float4*)&x[(size_t)(tb + t) * Dd + kc * KCH + kf * 4];
        smA[(kf * 4 + 0) * PA + t] = g.x;
        smA[(kf * 4 + 1) * PA + t] = g.y;
        smA[(kf * 4 + 2) * PA + t] = g.z;
        smA[(kf * 4 + 3) * PA + t] = g.w;
      }
      // stage B chunk [32k][128s]
#pragma unroll
      for (int m = 0; m < 4; ++m) {
        int s = t0 + m * 32;
        float4 g = *(const float4*)&x[(size_t)(sb + s) * Dd + kc * KCH + kf * 4];
        smB[(kf * 4 + 0) * PB + s] = g.x;
        smB[(kf * 4 + 1) * PB + s] = g.y;
        smB[(kf * 4 + 2) * PB + s] = g.z;
        smB[(kf * 4 + 3) * PB + s] = g.w;
      }
      if (kc == 0 && tid < STILE) sqs_l[tid] = sq[sb + tid];
      __syncthreads();
#pragma unroll 2
      for (int k = 0; k < KCH; ++k) {
        float4 a0 = *(const float4*)&smA[k * PA + ty * 8];      // broadcast across tx
        float4 a1 = *(const float4*)&smA[k * PA + ty * 8 + 4];
        float4 b0 = *(const float4*)&smB[k * PB + tx * 8];
        float4 b1 = *(const float4*)&smB[k * PB + tx * 8 + 4];
        float av[8] = {a0.x, a0.y, a0.z, a0.w, a1.x, a1.y, a1.z, a1.w};
        float bv[8] = {b0.x, b0.y, b0.z, b0.w, b1.x, b1.y, b1.z, b1.w};
#pragma unroll
        for (int r = 0; r < 8; ++r)
#pragma unroll
          for (int c = 0; c < 8; ++c) acc[r * 8 + c] = fmaf(av[r], bv[c], acc[r * 8 + c]);
      }
    }
    __syncthreads();  // compute reads of smA/smB done -> safe to alias as dtile

    // two 64-source halves: write swizzled dtile, then all-thread scan
#pragma unroll
    for (int h = 0; h < 2; ++h) {
      if (h) __syncthreads();  // previous half's scan reads done
      if ((tx >> 3) == h) {
        int sloc = (tx & 7) * 8;
#pragma unroll
        for (int r = 0; r < 8; ++r) {
          int t = ty * 8 + r;
          int sw = r * 8;  // = (t&7)*8
#pragma unroll
          for (int c = 0; c < 2; ++c) {
            float4 o;
            o.x = acc[r * 8 + c * 4 + 0];
            o.y = acc[r * 8 + c * 4 + 1];
            o.z = acc[r * 8 + c * 4 + 2];
            o.w = acc[r * 8 + c * 4 + 3];
            *(float4*)&smU[t * PDt + ((sloc + c * 4) ^ sw)] = o;
          }
        }
      }
      __syncthreads();
      int swz = (tg & 7) * 8;
      const float* drow = &smU[tg * PDt];
      const float* sqrow = &sqs_l[h * 64];
#pragma unroll 1
      for (int j = 0; j < 32; ++j) {
        int col = sl + 2 * j;  // ascending within thread -> tie keeps lower index
        float dot = drow[col ^ swz];
        float d = fmaf(-2.f, dot, sqi) + sqrow[col];
        int gidx = sb + h * 64 + col;
        if (d < bd[KK - 1]) {
#pragma unroll
          for (int p = KK - 1; p >= 1; --p) {
            bool shift = d < bd[p - 1];
            bool here = (!shift) && (d < bd[p]);
            float nb = shift ? bd[p - 1] : (here ? d : bd[p]);
            int ni = shift ? bi[p - 1] : (here ? gidx : bi[p]);
            bd[p] = nb;
            bi[p] = ni;
          }
          if (d < bd[0]) { bd[0] = d; bi[0] = gidx; }
        }
      }
    }
  }

  // block-end: merge the two parity lists per target -> sorted 16 per (target, split)
  __syncthreads();
  int* smUi = (int*)smU;
#pragma unroll
  for (int o = 0; o < KK; ++o) {
    smU[tid * KK + o] = bd[o];
    smUi[4096 + tid * KK + o] = bi[o];
  }
  __syncthreads();
  if (tid < TT) {
    const float* la = &smU[(2 * tid) * KK];
    const float* lb = &smU[(2 * tid + 1) * KK];
    const int* ia = &smUi[4096 + (2 * tid) * KK];
    const int* ib = &smUi[4096 + (2 * tid + 1) * KK];
    int pa = 0, pb = 0;
    size_t base = ((size_t)(tb + tid) * NSPLIT + split) * KK;
#pragma unroll
    for (int o = 0; o < KK; ++o) {
      float da = la[pa], db = lb[pb];
      int iaa = ia[pa], ibb = ib[pb];
      bool pick = (da < db) || (da == db && iaa < ibb);
      part_d[base + o] = pick ? da : db;
      part_i[base + o] = pick ? iaa : ibb;
      pa += pick ? 1 : 0;
      pb += pick ? 0 : 1;
    }
  }
}

__global__ void k_knn_merge(const float* __restrict__ part_d, const int* __restrict__ part_i,
                            int* __restrict__ knn_src) {
  int n = blockIdx.x * 256 + threadIdx.x;
  const float* pd = part_d + (size_t)n * NSPLIT * KK;
  const int* pi = part_i + (size_t)n * NSPLIT * KK;
  int pos[NSPLIT];
#pragma unroll
  for (int l = 0; l < NSPLIT; ++l) pos[l] = 0;
  for (int o = 0; o < KK; ++o) {
    float bestd = 3.3e38f;
    int besti = 0x7fffffff;
    int bestl = 0;
#pragma unroll
    for (int l = 0; l < NSPLIT; ++l) {
      if (pos[l] < KK) {
        float dd = pd[l * KK + pos[l]];
        int ii = pi[l * KK + pos[l]];
        if (dd < bestd || (dd == bestd && ii < besti)) { bestd = dd; besti = ii; bestl = l; }
      }
    }
    knn_src[n * KK + o] = besti;
#pragma unroll
    for (int l = 0; l < NSPLIT; ++l) pos[l] += (l == bestl) ? 1 : 0;
  }
}

// ---------------- fused 2-layer MLP cores (32 rows/block, H=256, out=128) ----------------
// smA: inT [k][32] (k<indim) during L1, then hidden [32 rows][pitch 260] fp32
// smB: weight K-chunk staging (2048 floats)
__device__ __forceinline__ void mlp_l1(int tid, int indim, const float* __restrict__ W1,
                                       const float* __restrict__ b1, float* smA, float* smB) {
  int rg = tid >> 5, cg = tid & 31;  // rows rg*4..+4, cols cg*8..+8
  float acc[32];
#pragma unroll
  for (int i = 0; i < 32; ++i) acc[i] = 0.f;
  for (int kc = 0; kc < indim / 8; ++kc) {
    const float* W1g = W1 + (size_t)kc * 8 * Hh;
    *(float4*)&smB[tid * 4] = *(const float4*)&W1g[tid * 4];
    *(float4*)&smB[1024 + tid * 4] = *(const float4*)&W1g[1024 + tid * 4];
    __syncthreads();
#pragma unroll
    for (int k = 0; k < 8; ++k) {
      int kk = kc * 8 + k;
      float4 a0 = *(const float4*)&smA[kk * 32 + rg * 4];
      float4 b0 = *(const float4*)&smB[k * Hh + cg * 8];
      float4 b1v = *(const float4*)&smB[k * Hh + cg * 8 + 4];
      float av[4] = {a0.x, a0.y, a0.z, a0.w};
      float bv[8] = {b0.x, b0.y, b0.z, b0.w, b1v.x, b1v.y, b1v.z, b1v.w};
#pragma unroll
      for (int rr = 0; rr < 4; ++rr)
#pragma unroll
        for (int cc = 0; cc < 8; ++cc) acc[rr * 8 + cc] += av[rr] * bv[cc];
    }
    __syncthreads();
  }
  float4 bb0 = *(const float4*)&b1[cg * 8];
  float4 bb1 = *(const float4*)&b1[cg * 8 + 4];
  float bs[8] = {bb0.x, bb0.y, bb0.z, bb0.w, bb1.x, bb1.y, bb1.z, bb1.w};
#pragma unroll
  for (int rr = 0; rr < 4; ++rr) {
    int row = rg * 4 + rr;
    float4 h0, h1;
    h0.x = fmaxf(acc[rr * 8 + 0] + bs[0], 0.f);
    h0.y = fmaxf(acc[rr * 8 + 1] + bs[1], 0.f);
    h0.z = fmaxf(acc[rr * 8 + 2] + bs[2], 0.f);
    h0.w = fmaxf(acc[rr * 8 + 3] + bs[3], 0.f);
    h1.x = fmaxf(acc[rr * 8 + 4] + bs[4], 0.f);
    h1.y = fmaxf(acc[rr * 8 + 5] + bs[5], 0.f);
    h1.z = fmaxf(acc[rr * 8 + 6] + bs[6], 0.f);
    h1.w = fmaxf(acc[rr * 8 + 7] + bs[7], 0.f);
    *(float4*)&smA[row * 260 + cg * 8] = h0;
    *(float4*)&smA[row * 260 + cg * 8 + 4] = h1;
  }
  __syncthreads();
}

__device__ __forceinline__ void mlp_l2(int tid, const float* __restrict__ W2,
                                       const float* smA, float* smB, float acc2[16]) {
  int rg2 = tid >> 5, cg2 = tid & 31;  // rows rg2*4..+4, cols cg2*4..+4
#pragma unroll
  for (int i = 0; i < 16; ++i) acc2[i] = 0.f;
  for (int kc = 0; kc < Hh / 16; ++kc) {
    const float* W2g = W2 + (size_t)kc * 16 * Dd;
    *(float4*)&smB[tid * 4] = *(const float4*)&W2g[tid * 4];
    *(float4*)&smB[1024 + tid * 4] = *(const float4*)&W2g[1024 + tid * 4];
    __syncthreads();
#pragma unroll
    for (int k = 0; k < 16; ++k) {
      int kk = kc * 16 + k;
      float4 b0 = *(const float4*)&smB[k * Dd + cg2 * 4];
#pragma unroll
      for (int rr = 0; rr < 4; ++rr) {
        float a = smA[(rg2 * 4 + rr) * 260 + kk];
        acc2[rr * 4 + 0] += a * b0.x;
        acc2[rr * 4 + 1] += a * b0.y;
        acc2[rr * 4 + 2] += a * b0.z;
        acc2[rr * 4 + 3] += a * b0.w;
      }
    }
    __syncthreads();
  }
}

// ---------------- static message MLP + grouped scatter-add ----------------
__global__ __launch_bounds__(256, 3) void k_static_msg(
    const float* __restrict__ xs, const float* __restrict__ ea, const int* __restrict__ ei,
    const int* __restrict__ mode_p, const int* __restrict__ perm, const int* __restrict__ dstS,
    const float* __restrict__ W1, const float* __restrict__ b1, const float* __restrict__ W2,
    const float* __restrict__ b2, float* __restrict__ agg) {
  __shared__ float smA[32 * 260];
  __shared__ float smB[2048];
  __shared__ int dstLoc[32];
  int tid = threadIdx.x;
  int pb = blockIdx.x * 32;
  int mode = *mode_p;
  int r = tid & 31, q = tid >> 5;
  int p = pb + r;
  int e = perm[p];
  int ds = dstS[p];
  int sr = ld_src(ei, e, mode);
  if (q == 0) dstLoc[r] = ds;
  const float* eap = ea + (size_t)e * DEe;
#pragma unroll
  for (int m = 0; m < 2; ++m) {
    int k0 = q * 8 + m * 4;
    float4 v = *(const float4*)&eap[k0];
    smA[(k0 + 0) * 32 + r] = v.x;
    smA[(k0 + 1) * 32 + r] = v.y;
    smA[(k0 + 2) * 32 + r] = v.z;
    smA[(k0 + 3) * 32 + r] = v.w;
  }
  const float* xsp = xs + (size_t)sr * Dd;
  const float* xdp = xs + (size_t)ds * Dd;
#pragma unroll
  for (int m = 0; m < 4; ++m) {
    int f0 = q * 16 + m * 4;
    float4 a = *(const float4*)&xsp[f0];
    float4 b = *(const float4*)&xdp[f0];
    smA[(DEe + f0 + 0) * 32 + r] = a.x - b.x;
    smA[(DEe + f0 + 1) * 32 + r] = a.y - b.y;
    smA[(DEe + f0 + 2) * 32 + r] = a.z - b.z;
    smA[(DEe + f0 + 3) * 32 + r] = a.w - b.w;
  }
  __syncthreads();
  mlp_l1(tid, DEe + Dd, W1, b1, smA, smB);
  float acc2[16];
  mlp_l2(tid, W2, smA, smB, acc2);
  int rg2 = tid >> 5, cg2 = tid & 31;
  float4 ob = *(const float4*)&b2[cg2 * 4];
#pragma unroll
  for (int rr = 0; rr < 4; ++rr) {
    int row = rg2 * 4 + rr;
    float4 o;
    o.x = fmaxf(acc2[rr * 4 + 0] + ob.x, 0.f);
    o.y = fmaxf(acc2[rr * 4 + 1] + ob.y, 0.f);
    o.z = fmaxf(acc2[rr * 4 + 2] + ob.z, 0.f);
    o.w = fmaxf(acc2[rr * 4 + 3] + ob.w, 0.f);
    *(float4*)&smA[row * 132 + cg2 * 4] = o;  // outT [32][132]
  }
  __syncthreads();
  int col = tid & 127, half = tid >> 7;
  int r0 = half * 16;
  float run = smA[r0 * 132 + col];
  int prevd = dstLoc[r0];
  for (int rr = 1; rr < 16; ++rr) {
    int row = r0 + rr;
    int dd2 = dstLoc[row];
    float v = smA[row * 132 + col];
    if (dd2 != prevd) {
      atomicAdd(&agg[(size_t)prevd * Dd + col], run);
      run = v;
      prevd = dd2;
    } else {
      run += v;
    }
  }
  atomicAdd(&agg[(size_t)prevd * Dd + col], run);
}

// ---------------- dynamic (kNN) message MLP, atomic-free aggregation ----------------
__global__ __launch_bounds__(256, 3) void k_dyn_msg(
    const float* __restrict__ xd, const int* __restrict__ knn, const float* __restrict__ W1,
    const float* __restrict__ b1, const float* __restrict__ W2, const float* __restrict__ b2,
    float* __restrict__ agg) {
  __shared__ float smA[32 * 260];
  __shared__ float smB[2048];
  __shared__ float pbuf[4 * 128];
  int tid = threadIdx.x;
  int nb2 = blockIdx.x * 2;  // 2 targets, 16 messages each = 32 rows
  int r = tid & 31, q = tid >> 5;
  int tgt = nb2 + (r >> 4);
  int nj = knn[tgt * KK + (r & 15)];
  const float* xip = xd + (size_t)tgt * Dd;
  const float* xjp = xd + (size_t)nj * Dd;
#pragma unroll
  for (int m = 0; m < 4; ++m) {
    int f0 = q * 16 + m * 4;
    float4 v = *(const float4*)&xip[f0];
    float4 a = *(const float4*)&xjp[f0];
    smA[(f0 + 0) * 32 + r] = v.x;
    smA[(f0 + 1) * 32 + r] = v.y;
    smA[(f0 + 2) * 32 + r] = v.z;
    smA[(f0 + 3) * 32 + r] = v.w;
    smA[(Dd + f0 + 0) * 32 + r] = a.x - v.x;
    smA[(Dd + f0 + 1) * 32 + r] = a.y - v.y;
    smA[(Dd + f0 + 2) * 32 + r] = a.z - v.z;
    smA[(Dd + f0 + 3) * 32 + r] = a.w - v.w;
  }
  __syncthreads();
  mlp_l1(tid, 2 * Dd, W1, b1, smA, smB);
  float acc2[16];
  mlp_l2(tid, W2, smA, smB, acc2);
  int rg2 = tid >> 5, cg2 = tid & 31;
  float4 ob = *(const float4*)&b2[cg2 * 4];
  float s0 = 0.f, s1 = 0.f, s2 = 0.f, s3 = 0.f;
#pragma unroll
  for (int rr = 0; rr < 4; ++rr) {
    s0 += fmaxf(acc2[rr * 4 + 0] + ob.x, 0.f);
    s1 += fmaxf(acc2[rr * 4 + 1] + ob.y, 0.f);
    s2 += fmaxf(acc2[rr * 4 + 2] + ob.z, 0.f);
    s3 += fmaxf(acc2[rr * 4 + 3] + ob.w, 0.f);
  }
  s0 += __shfl_xor(s0, 32);
  s1 += __shfl_xor(s1, 32);
  s2 += __shfl_xor(s2, 32);
  s3 += __shfl_xor(s3, 32);
  if ((rg2 & 1) == 0) {
    float4 o;
    o.x = s0; o.y = s1; o.z = s2; o.w = s3;
    *(float4*)&pbuf[(rg2 >> 1) * 128 + cg2 * 4] = o;
  }
  __syncthreads();
  int c = tid & 127, g = tid >> 7;
  float v = pbuf[(g * 2) * 128 + c] + pbuf[(g * 2 + 1) * 128 + c];
  agg[(size_t)(nb2 + g) * Dd + c] = v;
}

// ---------------- generic node MLP (update / fuse) ----------------
__global__ __launch_bounds__(256, 3) void k_node_mlp2(
    const float* __restrict__ in1, const float* __restrict__ in2, int indim,
    const float* __restrict__ W1, const float* __restrict__ b1, const float* __restrict__ W2,
    const float* __restrict__ b2, float* __restrict__ out) {
  __shared__ float smA[32 * 260];
  __shared__ float smB[2048];
  int tid = threadIdx.x;
  int nb = blockIdx.x * 32;
  int r = tid & 31, q = tid >> 5;
  for (int pass = 0; pass < indim / 32; ++pass) {
    int k0 = pass * 32 + q * 4;
    float4 v;
    if (k0 < Dd)
      v = *(const float4*)&in1[(size_t)(nb + r) * Dd + k0];
    else
      v = *(const float4*)&in2[(size_t)(nb + r) * Dd + (k0 - Dd)];
    smA[(k0 + 0) * 32 + r] = v.x;
    smA[(k0 + 1) * 32 + r] = v.y;
    smA[(k0 + 2) * 32 + r] = v.z;
    smA[(k0 + 3) * 32 + r] = v.w;
  }
  __syncthreads();
  mlp_l1(tid, indim, W1, b1, smA, smB);
  float acc2[16];
  mlp_l2(tid, W2, smA, smB, acc2);
  int rg2 = tid >> 5, cg2 = tid & 31;
  float4 ob = *(const float4*)&b2[cg2 * 4];
#pragma unroll
  for (int rr = 0; rr < 4; ++rr) {
    float4 o;
    o.x = fmaxf(acc2[rr * 4 + 0] + ob.x, 0.f);
    o.y = fmaxf(acc2[rr * 4 + 1] + ob.y, 0.f);
    o.z = fmaxf(acc2[rr * 4 + 2] + ob.z, 0.f);
    o.w = fmaxf(acc2[rr * 4 + 3] + ob.w, 0.f);
    *(float4*)&out[(size_t)(nb + rg2 * 4 + rr) * Dd + cg2 * 4] = o;
  }
}

// ---------------- edge refiner: ea = relu(ea @ rW + rb), 64->64 ----------------
__global__ __launch_bounds__(256) void k_refine(const float* __restrict__ ein,
                                                const float* __restrict__ rW,
                                                const float* __restrict__ rb,
                                                float* __restrict__ eout) {
  __shared__ float lea[16 * 64];
  __shared__ float ldsW[64 * 64];
  int tid = threadIdx.x;
  int eb = blockIdx.x * 16;
  *(float4*)&lea[tid * 4] = *(const float4*)&ein[(size_t)eb * DEe + tid * 4];
#pragma unroll
  for (int m = 0; m < 4; ++m) {
    int i4 = tid + m * 256;
    *(float4*)&ldsW[i4 * 4] = *(const float4*)&rW[i4 * 4];
  }
  __syncthreads();
  int j = tid & 63, eg = tid >> 6;  // thread: output col j for edges eg, eg+4, eg+8, eg+12
  float bias = rb[j];
  float acc0 = 0.f, acc1 = 0.f, acc2 = 0.f, acc3 = 0.f;
#pragma unroll 8
  for (int k = 0; k < 64; ++k) {
    float w = ldsW[k * 64 + j];
    acc0 += lea[(eg + 0) * 64 + k] * w;
    acc1 += lea[(eg + 4) * 64 + k] * w;
    acc2 += lea[(eg + 8) * 64 + k] * w;
    acc3 += lea[(eg + 12) * 64 + k] * w;
  }
  eout[(size_t)(eb + eg + 0) * DEe + j] = fmaxf(acc0 + bias, 0.f);
  eout[(size_t)(eb + eg + 4) * DEe + j] = fmaxf(acc1 + bias, 0.f);
  eout[(size_t)(eb + eg + 8) * DEe + j] = fmaxf(acc2 + bias, 0.f);
  eout[(size_t)(eb + eg + 12) * DEe + j] = fmaxf(acc3 + bias, 0.f);
}

extern "C" void kernel_launch(void* const* d_in, const int* in_sizes, int n_in, void* d_out,
                              int out_size, void* d_ws, size_t ws_size, hipStream_t stream) {
  (void)in_sizes; (void)n_in; (void)out_size; (void)ws_size;
  const float* x = (const float*)d_in[0];
  const float* edge_attr = (const float*)d_in[1];
  const float* sW1 = (const float*)d_in[2];
  const float* sb1 = (const float*)d_in[3];
  const float* sW2 = (const float*)d_in[4];
  const float* sb2 = (const float*)d_in[5];
  const float* uW1 = (const float*)d_in[6];
  const float* ub1 = (const float*)d_in[7];
  const float* uW2 = (const float*)d_in[8];
  const float* ub2 = (const float*)d_in[9];
  const float* rW = (const float*)d_in[10];
  const float* rb = (const float*)d_in[11];
  const float* dW1 = (const float*)d_in[12];
  const float* db1 = (const float*)d_in[13];
  const float* dW2 = (const float*)d_in[14];
  const float* db2 = (const float*)d_in[15];
  const float* dUW1 = (const float*)d_in[16];
  const float* dUb1 = (const float*)d_in[17];
  const float* dUW2 = (const float*)d_in[18];
  const float* dUb2 = (const float*)d_in[19];
  const float* fW1 = (const float*)d_in[20];
  const float* fb1 = (const float*)d_in[21];
  const float* fW2 = (const float*)d_in[22];
  const float* fb2 = (const float*)d_in[23];
  const int* ei = (const int*)d_in[24];
  float* out = (float*)d_out;

  float* wsf = (float*)d_ws;
  size_t off = 0;
  float* ea_ws = wsf + off; off += (size_t)Ee * DEe;
  float* xs_ws = wsf + off; off += (size_t)Nn * Dd;
  float* xd_ws = wsf + off; off += (size_t)Nn * Dd;
  float* agg = wsf + off;   off += (size_t)Nn * Dd;
  float* sq = wsf + off;    off += Nn;
  int* knn_src = (int*)(wsf + off); off += (size_t)Nn * KK;
  int* hist = (int*)(wsf + off);   off += Nn;
  int* cursor = (int*)(wsf + off); off += Nn;
  int* perm = (int*)(wsf + off);   off += Ee;
  int* dstS = (int*)(wsf + off);   off += Ee;
  int* modep = (int*)(wsf + off);  off += 1;
  // kNN partial lists overlap ea_ws: edge_attr refinement is dead before the dynamic branch runs
  float* part_d = ea_ws;
  int* part_i = (int*)(ea_ws + (size_t)Nn * NSPLIT * KK);

  // edge_index layout probe + counting sort by dst (CSR ordering)
  k_detect<<<1, 64, 0, stream>>>(ei, modep);
  hipMemsetAsync(hist, 0, Nn * sizeof(int), stream);
  k_hist<<<Ee / 256, 256, 0, stream>>>(ei, modep, hist);
  k_scan<<<1, 256, 0, stream>>>(hist, cursor);
  k_scatter<<<Ee / 256, 256, 0, stream>>>(ei, modep, cursor, perm, dstS);

  // ---- static branch: 3 convs + 2 refiners ----
  const float* xs_cur = x;
  const float* ea_cur = edge_attr;
  for (int i = 0; i < 3; ++i) {
    hipMemsetAsync(agg, 0, (size_t)Nn * Dd * sizeof(float), stream);
    k_static_msg<<<Ee / 32, 256, 0, stream>>>(
        xs_cur, ea_cur, ei, modep, perm, dstS, sW1 + (size_t)i * (DEe + Dd) * Hh,
        sb1 + (size_t)i * Hh, sW2 + (size_t)i * Hh * Dd, sb2 + (size_t)i * Dd, agg);
    k_node_mlp2<<<Nn / 32, 256, 0, stream>>>(
        agg, (const float*)nullptr, Dd, uW1 + (size_t)i * Dd * Hh, ub1 + (size_t)i * Hh,
        uW2 + (size_t)i * Hh * Dd, ub2 + (size_t)i * Dd, xs_ws);
    xs_cur = xs_ws;
    if (i < 2) {
      k_refine<<<Ee / 16, 256, 0, stream>>>(ea_cur, rW + (size_t)i * DEe * DEe,
                                            rb + (size_t)i * DEe, ea_ws);
      ea_cur = ea_ws;
    }
  }

  // ---- dynamic branch: 2 kNN convs ----
  const float* xd_cur = x;
  for (int i = 0; i < 2; ++i) {
    k_sq<<<Nn / 256, 256, 0, stream>>>(xd_cur, sq);
    k_knn_part<<<(Nn / TT) * NSPLIT, 256, 0, stream>>>(xd_cur, sq, part_d, part_i);
    k_knn_merge<<<Nn / 256, 256, 0, stream>>>(part_d, part_i, knn_src);
    k_dyn_msg<<<Nn / 2, 256, 0, stream>>>(
        xd_cur, knn_src, dW1 + (size_t)i * 2 * Dd * Hh, db1 + (size_t)i * Hh,
        dW2 + (size_t)i * Hh * Dd, db2 + (size_t)i * Dd, agg);
    k_node_mlp2<<<Nn / 32, 256, 0, stream>>>(
        agg, (const float*)nullptr, Dd, dUW1 + (size_t)i * Dd * Hh, dUb1 + (size_t)i * Hh,
        dUW2 + (size_t)i * Hh * Dd, dUb2 + (size_t)i * Dd, xd_ws);
    xd_cur = xd_ws;
  }

  // ---- fuse MLP: concat(xs, xd) 256 -> 256 -> 128 ----
  k_node_mlp2<<<Nn / 32, 256, 0, stream>>>(xs_ws, xd_ws, 2 * Dd, fW1, fb1, fW2, fb2, out);
}

// Round 4
// 4553.714 us; speedup vs baseline: 2.0635x; 1.4321x over previous
//
#include <hip/hip_runtime.h>

#define Nn 16384
#define Ee 262144
#define Dd 128
#define DEe 64
#define Hh 256
#define KK 16
#define NSPLIT 16
#define TT 128      /* knn targets per block */
#define STILE 128   /* knn source tile */
#define KCH 32      /* knn k chunk */
#define SWEEP (Nn / NSPLIT)
#define PA 132
#define PB 132
#define PDt 68

typedef __attribute__((ext_vector_type(8))) short short8;
typedef __attribute__((ext_vector_type(4))) float floatx4;

// ---------- bf16 helpers (RNE split: x = hi + lo) ----------
__device__ __forceinline__ ushort f2bf(float f) {
  uint u = __float_as_uint(f);
  u += 0x7fffu + ((u >> 16) & 1u);
  return (ushort)(u >> 16);
}
__device__ __forceinline__ float bf2f(ushort h) { return __uint_as_float(((uint)h) << 16); }
__device__ __forceinline__ void cvt_hilo(float4 v, uint2* hi, uint2* lo) {
  ushort h0 = f2bf(v.x), h1 = f2bf(v.y), h2 = f2bf(v.z), h3 = f2bf(v.w);
  ushort l0 = f2bf(v.x - bf2f(h0)), l1 = f2bf(v.y - bf2f(h1));
  ushort l2 = f2bf(v.z - bf2f(h2)), l3 = f2bf(v.w - bf2f(h3));
  hi->x = (uint)h0 | ((uint)h1 << 16); hi->y = (uint)h2 | ((uint)h3 << 16);
  lo->x = (uint)l0 | ((uint)l1 << 16); lo->y = (uint)l2 | ((uint)l3 << 16);
}

// edge_index access: mode=1 -> int32 layout, mode=0 -> int64 (low words at even positions)
__device__ __forceinline__ int ld_src(const int* ei, int e, int mode) {
  return mode ? ei[e] : ei[2 * e];
}
__device__ __forceinline__ int ld_dst(const int* ei, int e, int mode) {
  return mode ? ei[Ee + e] : ei[2 * Ee + 2 * e];
}

__global__ void k_detect(const int* __restrict__ ei, int* __restrict__ flag) {
  if (blockIdx.x == 0 && threadIdx.x == 0) {
    int any = 0;
    for (int i = 0; i < 64; ++i) any |= ei[2 * i + 1];
    *flag = (any != 0) ? 1 : 0;
  }
}

__global__ void k_hist(const int* __restrict__ ei, const int* __restrict__ mode_p,
                       int* __restrict__ hist) {
  int e = blockIdx.x * 256 + threadIdx.x;
  int mode = *mode_p;
  atomicAdd(&hist[ld_dst(ei, e, mode)], 1);
}

__global__ void k_scan(const int* __restrict__ hist, int* __restrict__ cursor) {
  __shared__ int part[256];
  __shared__ int partx[256];
  int t = threadIdx.x;
  int base = t * (Nn / 256);
  int s = 0;
  for (int i = 0; i < Nn / 256; ++i) s += hist[base + i];
  part[t] = s;
  __syncthreads();
  if (t == 0) {
    int run = 0;
    for (int i = 0; i < 256; ++i) { partx[i] = run; run += part[i]; }
  }
  __syncthreads();
  int run = partx[t];
  for (int i = 0; i < Nn / 256; ++i) { int v = hist[base + i]; cursor[base + i] = run; run += v; }
}

__global__ void k_scatter(const int* __restrict__ ei, const int* __restrict__ mode_p,
                          int* __restrict__ cursor, int* __restrict__ perm,
                          int* __restrict__ dstS) {
  int e = blockIdx.x * 256 + threadIdx.x;
  int mode = *mode_p;
  int d = ld_dst(ei, e, mode);
  int pos = atomicAdd(&cursor[d], 1);
  perm[pos] = e;
  dstS[pos] = d;
}

__global__ void k_sq(const float* __restrict__ x, float* __restrict__ sq) {
  int n = blockIdx.x * 256 + threadIdx.x;
  const float4* p = (const float4*)(x + (size_t)n * Dd);
  float acc = 0.f;
#pragma unroll
  for (int i = 0; i < Dd / 4; ++i) {
    float4 v = p[i];
    acc += v.x * v.x + v.y * v.y + v.z * v.z + v.w * v.w;
  }
  sq[n] = acc;
}

// ---- weight repack: fp32 [K][N] -> bf16 MFMA-B layout, K' = 2K (hi rows then lo rows) ----
// packed index: (( ntile*(K/16) + kstep )*64 + lane) -> uint4 of 8 bf16
// element j: k = (kstep%(K/32))*32 + (lane>>4)*8 + j ; n = ntile*16 + (lane&15)
__global__ void k_repack(const float* __restrict__ sW1, const float* __restrict__ sW2,
                         const float* __restrict__ dW1, const float* __restrict__ dW2,
                         uint4* __restrict__ out) {
  int gid = blockIdx.x * 256 + threadIdx.x;
  const float* W; int K, N, u, obase;
  if (gid < 36864) {
    int i = gid / 12288; u = gid - i * 12288;
    W = sW1 + (size_t)i * 49152; K = 192; N = 256; obase = i * 12288;
  } else if (gid < 61440) {
    int g = gid - 36864; int i = g / 8192; u = g - i * 8192;
    W = sW2 + (size_t)i * 32768; K = 256; N = 128; obase = 36864 + i * 8192;
  } else if (gid < 94208) {
    int g = gid - 61440; int i = g / 16384; u = g - i * 16384;
    W = dW1 + (size_t)i * 65536; K = 256; N = 256; obase = 61440 + i * 16384;
  } else if (gid < 110592) {
    int g = gid - 94208; int i = g / 8192; u = g - i * 8192;
    W = dW2 + (size_t)i * 32768; K = 256; N = 128; obase = 94208 + i * 8192;
  } else return;
  int lane = u & 63;
  int t = u >> 6;
  int ksteps = K / 16;
  int kstep = t % ksteps, ntile = t / ksteps;
  int R = K / 32;
  bool lo = kstep >= R;
  int k0 = (lo ? kstep - R : kstep) * 32 + (lane >> 4) * 8;
  int n = ntile * 16 + (lane & 15);
  ushort v[8];
#pragma unroll
  for (int j = 0; j < 8; ++j) {
    float w = W[(size_t)(k0 + j) * N + n];
    ushort h = f2bf(w);
    v[j] = lo ? f2bf(w - bf2f(h)) : h;
  }
  uint4 o;
  o.x = (uint)v[0] | ((uint)v[1] << 16);
  o.y = (uint)v[2] | ((uint)v[3] << 16);
  o.z = (uint)v[4] | ((uint)v[5] << 16);
  o.w = (uint)v[6] | ((uint)v[7] << 16);
  out[obase + u] = o;
}

// ---- bf16x3 MFMA GEMM core: M=32 (2 halves), wave n-slice = NT*16, K' = 2*RK*32 ----
// computes hi*Whi + lo*Whi + hi*Wlo into fp32 C (== fp32-accurate)
template <int RK, int NT>
__device__ __forceinline__ void mfma3(const ushort* aB, int pitch, const uint4* __restrict__ Wp,
                                      int lane, floatx4 C[2][NT]) {
  int q = lane >> 4, m0 = lane & 15;
  short8 ahc[RK][2];
#pragma unroll
  for (int hm = 0; hm < 2; ++hm)
#pragma unroll
    for (int nt = 0; nt < NT; ++nt)
#pragma unroll
      for (int rr = 0; rr < 4; ++rr) C[hm][nt][rr] = 0.f;
  // phase A: W_hi x (a_hi + a_lo)
#pragma unroll
  for (int s = 0; s < RK; ++s) {
    short8 ah0 = *(const short8*)(aB + m0 * pitch + s * 32 + q * 8);
    short8 ah1 = *(const short8*)(aB + (m0 + 16) * pitch + s * 32 + q * 8);
    short8 al0 = *(const short8*)(aB + m0 * pitch + (RK + s) * 32 + q * 8);
    short8 al1 = *(const short8*)(aB + (m0 + 16) * pitch + (RK + s) * 32 + q * 8);
    ahc[s][0] = ah0;
    ahc[s][1] = ah1;
#pragma unroll
    for (int nt = 0; nt < NT; ++nt) {
      uint4 bw = Wp[(nt * 2 * RK + s) * 64 + lane];
      short8 b = *(short8*)&bw;
      C[0][nt] = __builtin_amdgcn_mfma_f32_16x16x32_bf16(ah0, b, C[0][nt], 0, 0, 0);
      C[1][nt] = __builtin_amdgcn_mfma_f32_16x16x32_bf16(ah1, b, C[1][nt], 0, 0, 0);
      C[0][nt] = __builtin_amdgcn_mfma_f32_16x16x32_bf16(al0, b, C[0][nt], 0, 0, 0);
      C[1][nt] = __builtin_amdgcn_mfma_f32_16x16x32_bf16(al1, b, C[1][nt], 0, 0, 0);
    }
  }
  // phase B: W_lo x a_hi (cached)
#pragma unroll
  for (int s = 0; s < RK; ++s) {
#pragma unroll
    for (int nt = 0; nt < NT; ++nt) {
      uint4 bw = Wp[(nt * 2 * RK + RK + s) * 64 + lane];
      short8 b = *(short8*)&bw;
      C[0][nt] = __builtin_amdgcn_mfma_f32_16x16x32_bf16(ahc[s][0], b, C[0][nt], 0, 0, 0);
      C[1][nt] = __builtin_amdgcn_mfma_f32_16x16x32_bf16(ahc[s][1], b, C[1][nt], 0, 0, 0);
    }
  }
}

// ---- kNN: 128x128 per block, 8x8 reg tiles (unchanged from round 3) ----
__global__ __launch_bounds__(256, 3) void k_knn_part(const float* __restrict__ x,
                                                     const float* __restrict__ sq,
                                                     float* __restrict__ part_d,
                                                     int* __restrict__ part_i) {
  __shared__ float smU[TT * PDt];
  __shared__ float sqs_l[STILE];
  float* smA = smU;
  float* smB = smU + KCH * PA;
  int tid = threadIdx.x;
  int tileT = blockIdx.x >> 4;
  int split = blockIdx.x & 15;
  int tb = tileT * TT;
  int ty = tid >> 4, tx = tid & 15;
  int kf = tid & 7, t0 = tid >> 3;
  int tg = tid >> 1, sl = tid & 1;
  float sqi = sq[tb + tg];

  float bd[KK];
  int bi[KK];
#pragma unroll
  for (int p2 = 0; p2 < KK; ++p2) { bd[p2] = 3.0e38f; bi[p2] = 0x7fffffff; }

#pragma unroll 1
  for (int st = 0; st < SWEEP / STILE; ++st) {
    int sb = split * SWEEP + st * STILE;
    float acc[64];
#pragma unroll
    for (int i = 0; i < 64; ++i) acc[i] = 0.f;

#pragma unroll 1
    for (int kc = 0; kc < Dd / KCH; ++kc) {
      __syncthreads();
#pragma unroll
      for (int m = 0; m < 4; ++m) {
        int t = t0 + m * 32;
        float4 g = *(const float4*)&x[(size_t)(tb + t) * Dd + kc * KCH + kf * 4];
        smA[(kf * 4 + 0) * PA + t] = g.x;
        smA[(kf * 4 + 1) * PA + t] = g.y;
        smA[(kf * 4 + 2) * PA + t] = g.z;
        smA[(kf * 4 + 3) * PA + t] = g.w;
      }
#pragma unroll
      for (int m = 0; m < 4; ++m) {
        int s = t0 + m * 32;
        float4 g = *(const float4*)&x[(size_t)(sb + s) * Dd + kc * KCH + kf * 4];
        smB[(kf * 4 + 0) * PB + s] = g.x;
        smB[(kf * 4 + 1) * PB + s] = g.y;
        smB[(kf * 4 + 2) * PB + s] = g.z;
        smB[(kf * 4 + 3) * PB + s] = g.w;
      }
      if (kc == 0 && tid < STILE) sqs_l[tid] = sq[sb + tid];
      __syncthreads();
#pragma unroll 2
      for (int k = 0; k < KCH; ++k) {
        float4 a0 = *(const float4*)&smA[k * PA + ty * 8];
        float4 a1 = *(const float4*)&smA[k * PA + ty * 8 + 4];
        float4 b0 = *(const float4*)&smB[k * PB + tx * 8];
        float4 b1 = *(const float4*)&smB[k * PB + tx * 8 + 4];
        float av[8] = {a0.x, a0.y, a0.z, a0.w, a1.x, a1.y, a1.z, a1.w};
        float bv[8] = {b0.x, b0.y, b0.z, b0.w, b1.x, b1.y, b1.z, b1.w};
#pragma unroll
        for (int r = 0; r < 8; ++r)
#pragma unroll
          for (int c = 0; c < 8; ++c) acc[r * 8 + c] = fmaf(av[r], bv[c], acc[r * 8 + c]);
      }
    }
    __syncthreads();

#pragma unroll
    for (int h = 0; h < 2; ++h) {
      if (h) __syncthreads();
      if ((tx >> 3) == h) {
        int sloc = (tx & 7) * 8;
#pragma unroll
        for (int r = 0; r < 8; ++r) {
          int t = ty * 8 + r;
          int sw = r * 8;
#pragma unroll
          for (int c = 0; c < 2; ++c) {
            float4 o;
            o.x = acc[r * 8 + c * 4 + 0];
            o.y = acc[r * 8 + c * 4 + 1];
            o.z = acc[r * 8 + c * 4 + 2];
            o.w = acc[r * 8 + c * 4 + 3];
            *(float4*)&smU[t * PDt + ((sloc + c * 4) ^ sw)] = o;
          }
        }
      }
      __syncthreads();
      int swz = (tg & 7) * 8;
      const float* drow = &smU[tg * PDt];
      const float* sqrow = &sqs_l[h * 64];
#pragma unroll 1
      for (int j = 0; j < 32; ++j) {
        int col = sl + 2 * j;
        float dot = drow[col ^ swz];
        float d = fmaf(-2.f, dot, sqi) + sqrow[col];
        int gidx = sb + h * 64 + col;
        if (d < bd[KK - 1]) {
#pragma unroll
          for (int p = KK - 1; p >= 1; --p) {
            bool shift = d < bd[p - 1];
            bool here = (!shift) && (d < bd[p]);
            float nb = shift ? bd[p - 1] : (here ? d : bd[p]);
            int ni = shift ? bi[p - 1] : (here ? gidx : bi[p]);
            bd[p] = nb;
            bi[p] = ni;
          }
          if (d < bd[0]) { bd[0] = d; bi[0] = gidx; }
        }
      }
    }
  }

  __syncthreads();
  int* smUi = (int*)smU;
#pragma unroll
  for (int o = 0; o < KK; ++o) {
    smU[tid * KK + o] = bd[o];
    smUi[4096 + tid * KK + o] = bi[o];
  }
  __syncthreads();
  if (tid < TT) {
    const float* la = &smU[(2 * tid) * KK];
    const float* lb = &smU[(2 * tid + 1) * KK];
    const int* ia = &smUi[4096 + (2 * tid) * KK];
    const int* ib = &smUi[4096 + (2 * tid + 1) * KK];
    int pa = 0, pb = 0;
    size_t base = ((size_t)(tb + tid) * NSPLIT + split) * KK;
#pragma unroll
    for (int o = 0; o < KK; ++o) {
      float da = la[pa], db = lb[pb];
      int iaa = ia[pa], ibb = ib[pb];
      bool pick = (da < db) || (da == db && iaa < ibb);
      part_d[base + o] = pick ? da : db;
      part_i[base + o] = pick ? iaa : ibb;
      pa += pick ? 1 : 0;
      pb += pick ? 0 : 1;
    }
  }
}

__global__ void k_knn_merge(const float* __restrict__ part_d, const int* __restrict__ part_i,
                            int* __restrict__ knn_src) {
  int n = blockIdx.x * 256 + threadIdx.x;
  const float* pd = part_d + (size_t)n * NSPLIT * KK;
  const int* pi = part_i + (size_t)n * NSPLIT * KK;
  int pos[NSPLIT];
#pragma unroll
  for (int l = 0; l < NSPLIT; ++l) pos[l] = 0;
  for (int o = 0; o < KK; ++o) {
    float bestd = 3.3e38f;
    int besti = 0x7fffffff;
    int bestl = 0;
#pragma unroll
    for (int l = 0; l < NSPLIT; ++l) {
      if (pos[l] < KK) {
        float dd = pd[l * KK + pos[l]];
        int ii = pi[l * KK + pos[l]];
        if (dd < bestd || (dd == bestd && ii < besti)) { bestd = dd; besti = ii; bestl = l; }
      }
    }
    knn_src[n * KK + o] = besti;
#pragma unroll
    for (int l = 0; l < NSPLIT; ++l) pos[l] += (l == bestl) ? 1 : 0;
  }
}

// ---------------- static message MLP (bf16x3 MFMA) + grouped scatter-add ----------------
__global__ __launch_bounds__(256, 3) void k_static_msg(
    const float* __restrict__ xs, const float* __restrict__ ea, const int* __restrict__ ei,
    const int* __restrict__ mode_p, const int* __restrict__ perm, const int* __restrict__ dstS,
    const uint4* __restrict__ W1p, const float* __restrict__ b1,
    const uint4* __restrict__ W2p, const float* __restrict__ b2, float* __restrict__ agg) {
  __shared__ __align__(16) ushort smH[32 * 520];  // A1[32][392] / hidden[32][520] / msg f32[32][132]
  __shared__ int dstLoc[32];
  int tid = threadIdx.x;
  int wave = tid >> 6, lane = tid & 63;
  int pb = blockIdx.x * 32;
  int mode = *mode_p;
  int r = tid & 31, q8 = tid >> 5;
  int p = pb + r;
  int e = perm[p];
  int ds = dstS[p];
  int sr = ld_src(ei, e, mode);
  if (q8 == 0) dstLoc[r] = ds;
  const float* eap = ea + (size_t)e * DEe;
  const float* xsp = xs + (size_t)sr * Dd;
  const float* xdp = xs + (size_t)ds * Dd;
  // stage A1: row r, features 192, hi at k<192, lo at 192+k, pitch 392
#pragma unroll
  for (int it = 0; it < 6; ++it) {
    int f = q8 * 24 + it * 4;
    float4 v;
    if (f < 64) {
      v = *(const float4*)&eap[f];
    } else {
      float4 a = *(const float4*)&xsp[f - 64];
      float4 b = *(const float4*)&xdp[f - 64];
      v = make_float4(a.x - b.x, a.y - b.y, a.z - b.z, a.w - b.w);
    }
    uint2 hi, lo;
    cvt_hilo(v, &hi, &lo);
    *(uint2*)&smH[r * 392 + f] = hi;
    *(uint2*)&smH[r * 392 + 192 + f] = lo;
  }
  __syncthreads();
  // L1: 192 -> 256 (wave n-slice 64)
  floatx4 C1[2][4];
  mfma3<6, 4>(smH, 392, W1p + (size_t)wave * 4 * 12 * 64, lane, C1);
  __syncthreads();  // A1 dead -> reuse as hidden
  {
    int q = lane >> 4, n15 = lane & 15;
#pragma unroll
    for (int hm = 0; hm < 2; ++hm)
#pragma unroll
      for (int nt = 0; nt < 4; ++nt) {
        int n = wave * 64 + nt * 16 + n15;
        float bv = b1[n];
#pragma unroll
        for (int rr = 0; rr < 4; ++rr) {
          int m = hm * 16 + q * 4 + rr;
          float h = fmaxf(C1[hm][nt][rr] + bv, 0.f);
          ushort hh = f2bf(h);
          smH[m * 520 + n] = hh;
          smH[m * 520 + 256 + n] = f2bf(h - bf2f(hh));
        }
      }
  }
  __syncthreads();
  // L2: 256 -> 128 (wave n-slice 32)
  floatx4 C2[2][2];
  mfma3<8, 2>(smH, 520, W2p + (size_t)wave * 2 * 16 * 64, lane, C2);
  __syncthreads();  // hidden dead -> reuse as msg fp32
  float* smM = (float*)smH;
  {
    int q = lane >> 4, n15 = lane & 15;
#pragma unroll
    for (int hm = 0; hm < 2; ++hm)
#pragma unroll
      for (int nt = 0; nt < 2; ++nt) {
        int n = wave * 32 + nt * 16 + n15;
        float bv = b2[n];
#pragma unroll
        for (int rr = 0; rr < 4; ++rr) {
          int m = hm * 16 + q * 4 + rr;
          smM[m * 132 + n] = fmaxf(C2[hm][nt][rr] + bv, 0.f);
        }
      }
  }
  __syncthreads();
  // grouped scatter-add by dst (rows sorted by dst)
  int col = tid & 127, half = tid >> 7;
  int r0 = half * 16;
  float run = smM[r0 * 132 + col];
  int prevd = dstLoc[r0];
  for (int rr = 1; rr < 16; ++rr) {
    int row = r0 + rr;
    int dd2 = dstLoc[row];
    float v = smM[row * 132 + col];
    if (dd2 != prevd) {
      atomicAdd(&agg[(size_t)prevd * Dd + col], run);
      run = v;
      prevd = dd2;
    } else {
      run += v;
    }
  }
  atomicAdd(&agg[(size_t)prevd * Dd + col], run);
}

// ---------------- dynamic (kNN) message MLP (bf16x3 MFMA), atomic-free ----------------
__global__ __launch_bounds__(256, 3) void k_dyn_msg(
    const float* __restrict__ xd, const int* __restrict__ knn, const uint4* __restrict__ W1p,
    const float* __restrict__ b1, const uint4* __restrict__ W2p, const float* __restrict__ b2,
    float* __restrict__ agg) {
  __shared__ __align__(16) ushort smH[32 * 520];
  int tid = threadIdx.x;
  int wave = tid >> 6, lane = tid & 63;
  int nb2 = blockIdx.x * 2;
  int r = tid & 31, q8 = tid >> 5;
  int tgt = nb2 + (r >> 4);
  int nj = knn[tgt * KK + (r & 15)];
  const float* xip = xd + (size_t)tgt * Dd;
  const float* xjp = xd + (size_t)nj * Dd;
  // stage A: row r, 256 features [xi, xj-xi], hi at k<256, lo at 256+k, pitch 520
#pragma unroll
  for (int it = 0; it < 8; ++it) {
    int f = q8 * 32 + it * 4;
    float4 v;
    if (f < 128) {
      v = *(const float4*)&xip[f];
    } else {
      float4 a = *(const float4*)&xjp[f - 128];
      float4 b = *(const float4*)&xip[f - 128];
      v = make_float4(a.x - b.x, a.y - b.y, a.z - b.z, a.w - b.w);
    }
    uint2 hi, lo;
    cvt_hilo(v, &hi, &lo);
    *(uint2*)&smH[r * 520 + f] = hi;
    *(uint2*)&smH[r * 520 + 256 + f] = lo;
  }
  __syncthreads();
  // L1: 256 -> 256 (wave n-slice 64)
  floatx4 C1[2][4];
  mfma3<8, 4>(smH, 520, W1p + (size_t)wave * 4 * 16 * 64, lane, C1);
  __syncthreads();  // A dead -> hidden
  {
    int q = lane >> 4, n15 = lane & 15;
#pragma unroll
    for (int hm = 0; hm < 2; ++hm)
#pragma unroll
      for (int nt = 0; nt < 4; ++nt) {
        int n = wave * 64 + nt * 16 + n15;
        float bv = b1[n];
#pragma unroll
        for (int rr = 0; rr < 4; ++rr) {
          int m = hm * 16 + q * 4 + rr;
          float h = fmaxf(C1[hm][nt][rr] + bv, 0.f);
          ushort hh = f2bf(h);
          smH[m * 520 + n] = hh;
          smH[m * 520 + 256 + n] = f2bf(h - bf2f(hh));
        }
      }
  }
  __syncthreads();
  // L2: 256 -> 128 (wave n-slice 32)
  floatx4 C2[2][2];
  mfma3<8, 2>(smH, 520, W2p + (size_t)wave * 2 * 16 * 64, lane, C2);
  // epilogue: relu+bias per message, sum 16 messages per target (hm = local target)
  int q = lane >> 4, n15 = lane & 15;
#pragma unroll
  for (int hm = 0; hm < 2; ++hm)
#pragma unroll
    for (int nt = 0; nt < 2; ++nt) {
      int n = wave * 32 + nt * 16 + n15;
      float bv = b2[n];
      float s = 0.f;
#pragma unroll
      for (int rr = 0; rr < 4; ++rr) s += fmaxf(C2[hm][nt][rr] + bv, 0.f);
      s += __shfl_xor(s, 16);
      s += __shfl_xor(s, 32);
      if (q == 0) agg[(size_t)(nb2 + hm) * Dd + n] = s;
    }
}

// ---------------- fp32 fused 2-layer MLP core (node update / fuse) ----------------
__device__ __forceinline__ void mlp_l1(int tid, int indim, const float* __restrict__ W1,
                                       const float* __restrict__ b1, float* smA, float* smB) {
  int rg = tid >> 5, cg = tid & 31;
  float acc[32];
#pragma unroll
  for (int i = 0; i < 32; ++i) acc[i] = 0.f;
  for (int kc = 0; kc < indim / 8; ++kc) {
    const float* W1g = W1 + (size_t)kc * 8 * Hh;
    *(float4*)&smB[tid * 4] = *(const float4*)&W1g[tid * 4];
    *(float4*)&smB[1024 + tid * 4] = *(const float4*)&W1g[1024 + tid * 4];
    __syncthreads();
#pragma unroll
    for (int k = 0; k < 8; ++k) {
      int kk = kc * 8 + k;
      float4 a0 = *(const float4*)&smA[kk * 32 + rg * 4];
      float4 b0 = *(const float4*)&smB[k * Hh + cg * 8];
      float4 b1v = *(const float4*)&smB[k * Hh + cg * 8 + 4];
      float av[4] = {a0.x, a0.y, a0.z, a0.w};
      float bv[8] = {b0.x, b0.y, b0.z, b0.w, b1v.x, b1v.y, b1v.z, b1v.w};
#pragma unroll
      for (int rr = 0; rr < 4; ++rr)
#pragma unroll
        for (int cc = 0; cc < 8; ++cc) acc[rr * 8 + cc] += av[rr] * bv[cc];
    }
    __syncthreads();
  }
  float4 bb0 = *(const float4*)&b1[cg * 8];
  float4 bb1 = *(const float4*)&b1[cg * 8 + 4];
  float bs[8] = {bb0.x, bb0.y, bb0.z, bb0.w, bb1.x, bb1.y, bb1.z, bb1.w};
#pragma unroll
  for (int rr = 0; rr < 4; ++rr) {
    int row = rg * 4 + rr;
    float4 h0, h1;
    h0.x = fmaxf(acc[rr * 8 + 0] + bs[0], 0.f);
    h0.y = fmaxf(acc[rr * 8 + 1] + bs[1], 0.f);
    h0.z = fmaxf(acc[rr * 8 + 2] + bs[2], 0.f);
    h0.w = fmaxf(acc[rr * 8 + 3] + bs[3], 0.f);
    h1.x = fmaxf(acc[rr * 8 + 4] + bs[4], 0.f);
    h1.y = fmaxf(acc[rr * 8 + 5] + bs[5], 0.f);
    h1.z = fmaxf(acc[rr * 8 + 6] + bs[6], 0.f);
    h1.w = fmaxf(acc[rr * 8 + 7] + bs[7], 0.f);
    *(float4*)&smA[row * 260 + cg * 8] = h0;
    *(float4*)&smA[row * 260 + cg * 8 + 4] = h1;
  }
  __syncthreads();
}

__device__ __forceinline__ void mlp_l2(int tid, const float* __restrict__ W2,
                                       const float* smA, float* smB, float acc2[16]) {
  int rg2 = tid >> 5, cg2 = tid & 31;
#pragma unroll
  for (int i = 0; i < 16; ++i) acc2[i] = 0.f;
  for (int kc = 0; kc < Hh / 16; ++kc) {
    const float* W2g = W2 + (size_t)kc * 16 * Dd;
    *(float4*)&smB[tid * 4] = *(const float4*)&W2g[tid * 4];
    *(float4*)&smB[1024 + tid * 4] = *(const float4*)&W2g[1024 + tid * 4];
    __syncthreads();
#pragma unroll
    for (int k = 0; k < 16; ++k) {
      int kk = kc * 16 + k;
      float4 b0 = *(const float4*)&smB[k * Dd + cg2 * 4];
#pragma unroll
      for (int rr = 0; rr < 4; ++rr) {
        float a = smA[(rg2 * 4 + rr) * 260 + kk];
        acc2[rr * 4 + 0] += a * b0.x;
        acc2[rr * 4 + 1] += a * b0.y;
        acc2[rr * 4 + 2] += a * b0.z;
        acc2[rr * 4 + 3] += a * b0.w;
      }
    }
    __syncthreads();
  }
}

__global__ __launch_bounds__(256, 3) void k_node_mlp2(
    const float* __restrict__ in1, const float* __restrict__ in2, int indim,
    const float* __restrict__ W1, const float* __restrict__ b1, const float* __restrict__ W2,
    const float* __restrict__ b2, float* __restrict__ out) {
  __shared__ float smA[32 * 260];
  __shared__ float smB[2048];
  int tid = threadIdx.x;
  int nb = blockIdx.x * 32;
  int r = tid & 31, q = tid >> 5;
  for (int pass = 0; pass < indim / 32; ++pass) {
    int k0 = pass * 32 + q * 4;
    float4 v;
    if (k0 < Dd)
      v = *(const float4*)&in1[(size_t)(nb + r) * Dd + k0];
    else
      v = *(const float4*)&in2[(size_t)(nb + r) * Dd + (k0 - Dd)];
    smA[(k0 + 0) * 32 + r] = v.x;
    smA[(k0 + 1) * 32 + r] = v.y;
    smA[(k0 + 2) * 32 + r] = v.z;
    smA[(k0 + 3) * 32 + r] = v.w;
  }
  __syncthreads();
  mlp_l1(tid, indim, W1, b1, smA, smB);
  float acc2[16];
  mlp_l2(tid, W2, smA, smB, acc2);
  int rg2 = tid >> 5, cg2 = tid & 31;
  float4 ob = *(const float4*)&b2[cg2 * 4];
#pragma unroll
  for (int rr = 0; rr < 4; ++rr) {
    float4 o;
    o.x = fmaxf(acc2[rr * 4 + 0] + ob.x, 0.f);
    o.y = fmaxf(acc2[rr * 4 + 1] + ob.y, 0.f);
    o.z = fmaxf(acc2[rr * 4 + 2] + ob.z, 0.f);
    o.w = fmaxf(acc2[rr * 4 + 3] + ob.w, 0.f);
    *(float4*)&out[(size_t)(nb + rg2 * 4 + rr) * Dd + cg2 * 4] = o;
  }
}

__global__ __launch_bounds__(256) void k_refine(const float* __restrict__ ein,
                                                const float* __restrict__ rW,
                                                const float* __restrict__ rb,
                                                float* __restrict__ eout) {
  __shared__ float lea[16 * 64];
  __shared__ float ldsW[64 * 64];
  int tid = threadIdx.x;
  int eb = blockIdx.x * 16;
  *(float4*)&lea[tid * 4] = *(const float4*)&ein[(size_t)eb * DEe + tid * 4];
#pragma unroll
  for (int m = 0; m < 4; ++m) {
    int i4 = tid + m * 256;
    *(float4*)&ldsW[i4 * 4] = *(const float4*)&rW[i4 * 4];
  }
  __syncthreads();
  int j = tid & 63, eg = tid >> 6;
  float bias = rb[j];
  float acc0 = 0.f, acc1 = 0.f, acc2 = 0.f, acc3 = 0.f;
#pragma unroll 8
  for (int k = 0; k < 64; ++k) {
    float w = ldsW[k * 64 + j];
    acc0 += lea[(eg + 0) * 64 + k] * w;
    acc1 += lea[(eg + 4) * 64 + k] * w;
    acc2 += lea[(eg + 8) * 64 + k] * w;
    acc3 += lea[(eg + 12) * 64 + k] * w;
  }
  eout[(size_t)(eb + eg + 0) * DEe + j] = fmaxf(acc0 + bias, 0.f);
  eout[(size_t)(eb + eg + 4) * DEe + j] = fmaxf(acc1 + bias, 0.f);
  eout[(size_t)(eb + eg + 8) * DEe + j] = fmaxf(acc2 + bias, 0.f);
  eout[(size_t)(eb + eg + 12) * DEe + j] = fmaxf(acc3 + bias, 0.f);
}

extern "C" void kernel_launch(void* const* d_in, const int* in_sizes, int n_in, void* d_out,
                              int out_size, void* d_ws, size_t ws_size, hipStream_t stream) {
  (void)in_sizes; (void)n_in; (void)out_size; (void)ws_size;
  const float* x = (const float*)d_in[0];
  const float* edge_attr = (const float*)d_in[1];
  const float* sW1 = (const float*)d_in[2];
  const float* sb1 = (const float*)d_in[3];
  const float* sW2 = (const float*)d_in[4];
  const float* sb2 = (const float*)d_in[5];
  const float* uW1 = (const float*)d_in[6];
  const float* ub1 = (const float*)d_in[7];
  const float* uW2 = (const float*)d_in[8];
  const float* ub2 = (const float*)d_in[9];
  const float* rW = (const float*)d_in[10];
  const float* rb = (const float*)d_in[11];
  const float* dW1 = (const float*)d_in[12];
  const float* db1 = (const float*)d_in[13];
  const float* dW2 = (const float*)d_in[14];
  const float* db2 = (const float*)d_in[15];
  const float* dUW1 = (const float*)d_in[16];
  const float* dUb1 = (const float*)d_in[17];
  const float* dUW2 = (const float*)d_in[18];
  const float* dUb2 = (const float*)d_in[19];
  const float* fW1 = (const float*)d_in[20];
  const float* fb1 = (const float*)d_in[21];
  const float* fW2 = (const float*)d_in[22];
  const float* fb2 = (const float*)d_in[23];
  const int* ei = (const int*)d_in[24];
  float* out = (float*)d_out;

  float* wsf = (float*)d_ws;
  size_t off = 0;
  float* ea_ws = wsf + off; off += (size_t)Ee * DEe;
  float* xs_ws = wsf + off; off += (size_t)Nn * Dd;
  float* xd_ws = wsf + off; off += (size_t)Nn * Dd;
  float* agg = wsf + off;   off += (size_t)Nn * Dd;
  float* sq = wsf + off;    off += Nn;
  int* knn_src = (int*)(wsf + off); off += (size_t)Nn * KK;
  int* hist = (int*)(wsf + off);   off += Nn;
  int* cursor = (int*)(wsf + off); off += Nn;
  int* perm = (int*)(wsf + off);   off += Ee;
  int* dstS = (int*)(wsf + off);   off += Ee;
  int* modep = (int*)(wsf + off);  off += 1;
  off = (off + 3) & ~(size_t)3;  // 16B align for uint4
  uint4* wpk = (uint4*)(wsf + off); off += (size_t)110592 * 4;
  // kNN partial lists overlap ea_ws (edge_attr refinement dead before dynamic branch)
  float* part_d = ea_ws;
  int* part_i = (int*)(ea_ws + (size_t)Nn * NSPLIT * KK);

  // edge_index probe + counting sort by dst
  k_detect<<<1, 64, 0, stream>>>(ei, modep);
  hipMemsetAsync(hist, 0, Nn * sizeof(int), stream);
  k_hist<<<Ee / 256, 256, 0, stream>>>(ei, modep, hist);
  k_scan<<<1, 256, 0, stream>>>(hist, cursor);
  k_scatter<<<Ee / 256, 256, 0, stream>>>(ei, modep, cursor, perm, dstS);

  // repack all msg-MLP weights into bf16 hi/lo MFMA-B layout
  k_repack<<<432, 256, 0, stream>>>(sW1, sW2, dW1, dW2, wpk);

  // ---- static branch: 3 convs + 2 refiners ----
  const float* xs_cur = x;
  const float* ea_cur = edge_attr;
  for (int i = 0; i < 3; ++i) {
    hipMemsetAsync(agg, 0, (size_t)Nn * Dd * sizeof(float), stream);
    k_static_msg<<<Ee / 32, 256, 0, stream>>>(
        xs_cur, ea_cur, ei, modep, perm, dstS, wpk + (size_t)i * 12288,
        sb1 + (size_t)i * Hh, wpk + 36864 + (size_t)i * 8192, sb2 + (size_t)i * Dd, agg);
    k_node_mlp2<<<Nn / 32, 256, 0, stream>>>(
        agg, (const float*)nullptr, Dd, uW1 + (size_t)i * Dd * Hh, ub1 + (size_t)i * Hh,
        uW2 + (size_t)i * Hh * Dd, ub2 + (size_t)i * Dd, xs_ws);
    xs_cur = xs_ws;
    if (i < 2) {
      k_refine<<<Ee / 16, 256, 0, stream>>>(ea_cur, rW + (size_t)i * DEe * DEe,
                                            rb + (size_t)i * DEe, ea_ws);
      ea_cur = ea_ws;
    }
  }

  // ---- dynamic branch: 2 kNN convs ----
  const float* xd_cur = x;
  for (int i = 0; i < 2; ++i) {
    k_sq<<<Nn / 256, 256, 0, stream>>>(xd_cur, sq);
    k_knn_part<<<(Nn / TT) * NSPLIT, 256, 0, stream>>>(xd_cur, sq, part_d, part_i);
    k_knn_merge<<<Nn / 256, 256, 0, stream>>>(part_d, part_i, knn_src);
    k_dyn_msg<<<Nn / 2, 256, 0, stream>>>(
        xd_cur, knn_src, wpk + 61440 + (size_t)i * 16384, db1 + (size_t)i * Hh,
        wpk + 94208 + (size_t)i * 8192, db2 + (size_t)i * Dd, agg);
    k_node_mlp2<<<Nn / 32, 256, 0, stream>>>(
        agg, (const float*)nullptr, Dd, dUW1 + (size_t)i * Dd * Hh, dUb1 + (size_t)i * Hh,
        dUW2 + (size_t)i * Hh * Dd, dUb2 + (size_t)i * Dd, xd_ws);
    xd_cur = xd_ws;
  }

  // ---- fuse MLP ----
  k_node_mlp2<<<Nn / 32, 256, 0, stream>>>(xs_ws, xd_ws, 2 * Dd, fW1, fb1, fW2, fb2, out);
}

// Round 6
// 3765.414 us; speedup vs baseline: 2.4955x; 1.2094x over previous
//
#include <hip/hip_runtime.h>

#define Nn 16384
#define Ee 262144
#define Dd 128
#define DEe 64
#define Hh 256
#define KK 16
#define NSPLIT 16
#define TT 128      /* knn targets per block */
#define STILE 128   /* knn source tile */
#define SWEEP (Nn / NSPLIT)
#define PXS 136     /* bf16 source-tile pitch (ushorts) */
#define PDD 66      /* dtile pitch (floats) */
#define MCAND 32    /* rerank candidates per target */

typedef __attribute__((ext_vector_type(8))) short short8;
typedef __attribute__((ext_vector_type(4))) float floatx4;

// ---------- bf16 helpers ----------
__device__ __forceinline__ ushort f2bf(float f) {
  uint u = __float_as_uint(f);
  u += 0x7fffu + ((u >> 16) & 1u);
  return (ushort)(u >> 16);
}
__device__ __forceinline__ float bf2f(ushort h) { return __uint_as_float(((uint)h) << 16); }
__device__ __forceinline__ void cvt_hilo(float4 v, uint2* hi, uint2* lo) {
  ushort h0 = f2bf(v.x), h1 = f2bf(v.y), h2 = f2bf(v.z), h3 = f2bf(v.w);
  ushort l0 = f2bf(v.x - bf2f(h0)), l1 = f2bf(v.y - bf2f(h1));
  ushort l2 = f2bf(v.z - bf2f(h2)), l3 = f2bf(v.w - bf2f(h3));
  hi->x = (uint)h0 | ((uint)h1 << 16); hi->y = (uint)h2 | ((uint)h3 << 16);
  lo->x = (uint)l0 | ((uint)l1 << 16); lo->y = (uint)l2 | ((uint)l3 << 16);
}
__device__ __forceinline__ uint4 pk8(float4 a, float4 b) {
  uint4 o;
  o.x = (uint)f2bf(a.x) | ((uint)f2bf(a.y) << 16);
  o.y = (uint)f2bf(a.z) | ((uint)f2bf(a.w) << 16);
  o.z = (uint)f2bf(b.x) | ((uint)f2bf(b.y) << 16);
  o.w = (uint)f2bf(b.z) | ((uint)f2bf(b.w) << 16);
  return o;
}

// edge_index access: mode=1 -> int32 layout, mode=0 -> int64 (low words at even positions)
__device__ __forceinline__ int ld_src(const int* ei, int e, int mode) {
  return mode ? ei[e] : ei[2 * e];
}
__device__ __forceinline__ int ld_dst(const int* ei, int e, int mode) {
  return mode ? ei[Ee + e] : ei[2 * Ee + 2 * e];
}

__global__ void k_detect(const int* __restrict__ ei, int* __restrict__ flag) {
  if (blockIdx.x == 0 && threadIdx.x == 0) {
    int any = 0;
    for (int i = 0; i < 64; ++i) any |= ei[2 * i + 1];
    *flag = (any != 0) ? 1 : 0;
  }
}

__global__ void k_hist(const int* __restrict__ ei, const int* __restrict__ mode_p,
                       int* __restrict__ hist) {
  int e = blockIdx.x * 256 + threadIdx.x;
  int mode = *mode_p;
  atomicAdd(&hist[ld_dst(ei, e, mode)], 1);
}

__global__ void k_scan(const int* __restrict__ hist, int* __restrict__ cursor) {
  __shared__ int part[256];
  __shared__ int partx[256];
  int t = threadIdx.x;
  int base = t * (Nn / 256);
  int s = 0;
  for (int i = 0; i < Nn / 256; ++i) s += hist[base + i];
  part[t] = s;
  __syncthreads();
  if (t == 0) {
    int run = 0;
    for (int i = 0; i < 256; ++i) { partx[i] = run; run += part[i]; }
  }
  __syncthreads();
  int run = partx[t];
  for (int i = 0; i < Nn / 256; ++i) { int v = hist[base + i]; cursor[base + i] = run; run += v; }
}

__global__ void k_scatter(const int* __restrict__ ei, const int* __restrict__ mode_p,
                          int* __restrict__ cursor, int* __restrict__ perm,
                          int* __restrict__ dstS) {
  int e = blockIdx.x * 256 + threadIdx.x;
  int mode = *mode_p;
  int d = ld_dst(ei, e, mode);
  int pos = atomicAdd(&cursor[d], 1);
  perm[pos] = e;
  dstS[pos] = d;
}

__global__ void k_sq(const float* __restrict__ x, float* __restrict__ sq) {
  int n = blockIdx.x * 256 + threadIdx.x;
  const float4* p = (const float4*)(x + (size_t)n * Dd);
  float acc = 0.f;
#pragma unroll
  for (int i = 0; i < Dd / 4; ++i) {
    float4 v = p[i];
    acc += v.x * v.x + v.y * v.y + v.z * v.z + v.w * v.w;
  }
  sq[n] = acc;
}

// ---- weight repack: fp32 [K][N] -> bf16 MFMA-B layout, K' = 2K (hi rows then lo rows) ----
__global__ void k_repack(const float* __restrict__ sW1, const float* __restrict__ sW2,
                         const float* __restrict__ dW1, const float* __restrict__ dW2,
                         uint4* __restrict__ out) {
  int gid = blockIdx.x * 256 + threadIdx.x;
  const float* W; int K, N, u, obase;
  if (gid < 36864) {
    int i = gid / 12288; u = gid - i * 12288;
    W = sW1 + (size_t)i * 49152; K = 192; N = 256; obase = i * 12288;
  } else if (gid < 61440) {
    int g = gid - 36864; int i = g / 8192; u = g - i * 8192;
    W = sW2 + (size_t)i * 32768; K = 256; N = 128; obase = 36864 + i * 8192;
  } else if (gid < 94208) {
    int g = gid - 61440; int i = g / 16384; u = g - i * 16384;
    W = dW1 + (size_t)i * 65536; K = 256; N = 256; obase = 61440 + i * 16384;
  } else if (gid < 110592) {
    int g = gid - 94208; int i = g / 8192; u = g - i * 8192;
    W = dW2 + (size_t)i * 32768; K = 256; N = 128; obase = 94208 + i * 8192;
  } else return;
  int lane = u & 63;
  int t = u >> 6;
  int ksteps = K / 16;
  int kstep = t % ksteps, ntile = t / ksteps;
  int R = K / 32;
  bool lo = kstep >= R;
  int k0 = (lo ? kstep - R : kstep) * 32 + (lane >> 4) * 8;
  int n = ntile * 16 + (lane & 15);
  ushort v[8];
#pragma unroll
  for (int j = 0; j < 8; ++j) {
    float w = W[(size_t)(k0 + j) * N + n];
    ushort h = f2bf(w);
    v[j] = lo ? f2bf(w - bf2f(h)) : h;
  }
  uint4 o;
  o.x = (uint)v[0] | ((uint)v[1] << 16);
  o.y = (uint)v[2] | ((uint)v[3] << 16);
  o.z = (uint)v[4] | ((uint)v[5] << 16);
  o.w = (uint)v[6] | ((uint)v[7] << 16);
  out[obase + u] = o;
}

// ---- bf16x3 MFMA GEMM core for MLPs ----
template <int RK, int NT>
__device__ __forceinline__ void mfma3(const ushort* aB, int pitch, const uint4* __restrict__ Wp,
                                      int lane, floatx4 C[2][NT]) {
  int q = lane >> 4, m0 = lane & 15;
  short8 ahc[RK][2];
#pragma unroll
  for (int hm = 0; hm < 2; ++hm)
#pragma unroll
    for (int nt = 0; nt < NT; ++nt)
#pragma unroll
      for (int rr = 0; rr < 4; ++rr) C[hm][nt][rr] = 0.f;
#pragma unroll
  for (int s = 0; s < RK; ++s) {
    short8 ah0 = *(const short8*)(aB + m0 * pitch + s * 32 + q * 8);
    short8 ah1 = *(const short8*)(aB + (m0 + 16) * pitch + s * 32 + q * 8);
    short8 al0 = *(const short8*)(aB + m0 * pitch + (RK + s) * 32 + q * 8);
    short8 al1 = *(const short8*)(aB + (m0 + 16) * pitch + (RK + s) * 32 + q * 8);
    ahc[s][0] = ah0;
    ahc[s][1] = ah1;
#pragma unroll
    for (int nt = 0; nt < NT; ++nt) {
      uint4 bw = Wp[(nt * 2 * RK + s) * 64 + lane];
      short8 b = *(short8*)&bw;
      C[0][nt] = __builtin_amdgcn_mfma_f32_16x16x32_bf16(ah0, b, C[0][nt], 0, 0, 0);
      C[1][nt] = __builtin_amdgcn_mfma_f32_16x16x32_bf16(ah1, b, C[1][nt], 0, 0, 0);
      C[0][nt] = __builtin_amdgcn_mfma_f32_16x16x32_bf16(al0, b, C[0][nt], 0, 0, 0);
      C[1][nt] = __builtin_amdgcn_mfma_f32_16x16x32_bf16(al1, b, C[1][nt], 0, 0, 0);
    }
  }
#pragma unroll
  for (int s = 0; s < RK; ++s) {
#pragma unroll
    for (int nt = 0; nt < NT; ++nt) {
      uint4 bw = Wp[(nt * 2 * RK + RK + s) * 64 + lane];
      short8 b = *(short8*)&bw;
      C[0][nt] = __builtin_amdgcn_mfma_f32_16x16x32_bf16(ahc[s][0], b, C[0][nt], 0, 0, 0);
      C[1][nt] = __builtin_amdgcn_mfma_f32_16x16x32_bf16(ahc[s][1], b, C[1][nt], 0, 0, 0);
    }
  }
}

// ---- kNN prefilter: bf16 MFMA dots, approx top-16 per (target,split) ----
__global__ __launch_bounds__(256, 3) void k_knn_part(const float* __restrict__ x,
                                                     const float* __restrict__ sq,
                                                     float* __restrict__ part_d,
                                                     int* __restrict__ part_i) {
  __shared__ __align__(16) ushort smXS[128 * PXS];  // bf16 src tile / fp32 dtile / merge bufs
  __shared__ float sqs_l[STILE];
  float* dtile = (float*)smXS;            // [128][PDD]
  float* mbD = (float*)smXS;              // merge: 256*16 floats
  int* mbI = ((int*)smXS) + 4096;
  int tid = threadIdx.x;
  int wave = tid >> 6, lane = tid & 63;
  int quad = lane >> 4, n15 = lane & 15;
  int tileT = blockIdx.x >> 4;
  int split = blockIdx.x & 15;
  int tb = tileT * TT;
  int tg = tid >> 1, sl = tid & 1;
  float sqi = sq[tb + tg];

  // A-fragments in registers (targets fixed for whole block)
  short8 afr[2][4];
#pragma unroll
  for (int mt = 0; mt < 2; ++mt) {
    int row = tb + wave * 32 + mt * 16 + n15;
#pragma unroll
    for (int ks = 0; ks < 4; ++ks) {
      int k0 = ks * 32 + quad * 8;
      float4 a = *(const float4*)&x[(size_t)row * Dd + k0];
      float4 b = *(const float4*)&x[(size_t)row * Dd + k0 + 4];
      uint4 p = pk8(a, b);
      afr[mt][ks] = *(short8*)&p;
    }
  }

  float bd[KK];
  int bi[KK];
#pragma unroll
  for (int p2 = 0; p2 < KK; ++p2) { bd[p2] = 3.0e38f; bi[p2] = 0x7fffffff; }

#pragma unroll 1
  for (int st = 0; st < SWEEP / STILE; ++st) {
    int sb = split * SWEEP + st * STILE;
    __syncthreads();  // prior dtile/merge use of smXS done
    {
      int row = tid & 127, kh = (tid >> 7) * 64;
      int swz = ((row >> 3) & 7) << 3;
#pragma unroll
      for (int g = 0; g < 8; ++g) {
        int k0 = kh + g * 8;
        float4 a = *(const float4*)&x[(size_t)(sb + row) * Dd + k0];
        float4 b = *(const float4*)&x[(size_t)(sb + row) * Dd + k0 + 4];
        *(uint4*)&smXS[row * PXS + (k0 ^ swz)] = pk8(a, b);
      }
      if (tid < STILE) sqs_l[tid] = sq[sb + tid];
    }
    __syncthreads();
    floatx4 C[2][8];
#pragma unroll
    for (int mt = 0; mt < 2; ++mt)
#pragma unroll
      for (int nt = 0; nt < 8; ++nt)
#pragma unroll
        for (int rr = 0; rr < 4; ++rr) C[mt][nt][rr] = 0.f;
#pragma unroll
    for (int nt = 0; nt < 8; ++nt) {
      int s = nt * 16 + n15;
      int swz = ((s >> 3) & 7) << 3;
#pragma unroll
      for (int ks = 0; ks < 4; ++ks) {
        int k0 = ks * 32 + quad * 8;
        short8 bfr = *(const short8*)&smXS[s * PXS + (k0 ^ swz)];
        C[0][nt] = __builtin_amdgcn_mfma_f32_16x16x32_bf16(afr[0][ks], bfr, C[0][nt], 0, 0, 0);
        C[1][nt] = __builtin_amdgcn_mfma_f32_16x16x32_bf16(afr[1][ks], bfr, C[1][nt], 0, 0, 0);
      }
    }
    __syncthreads();  // xs reads done -> alias as dtile
#pragma unroll
    for (int h = 0; h < 2; ++h) {
      if (h) __syncthreads();
#pragma unroll
      for (int mt = 0; mt < 2; ++mt)
#pragma unroll
        for (int nt = 0; nt < 4; ++nt)
#pragma unroll
          for (int rr = 0; rr < 4; ++rr) {
            int row = wave * 32 + mt * 16 + quad * 4 + rr;
            int col = nt * 16 + n15;
            dtile[row * PDD + col] = C[mt][nt + 4 * h][rr];
          }
      __syncthreads();
      const float* drow = &dtile[tg * PDD];
      const float* sqrow = &sqs_l[h * 64];
#pragma unroll 1
      for (int j = 0; j < 32; ++j) {
        int col = sl + 2 * j;
        float dot = drow[col];
        float d = fmaf(-2.f, dot, sqi) + sqrow[col];
        int gidx = sb + h * 64 + col;
        if (d < bd[KK - 1]) {
#pragma unroll
          for (int p = KK - 1; p >= 1; --p) {
            bool shift = d < bd[p - 1];
            bool here = (!shift) && (d < bd[p]);
            float nb = shift ? bd[p - 1] : (here ? d : bd[p]);
            int ni = shift ? bi[p - 1] : (here ? gidx : bi[p]);
            bd[p] = nb;
            bi[p] = ni;
          }
          if (d < bd[0]) { bd[0] = d; bi[0] = gidx; }
        }
      }
    }
  }

  // block-end: merge the two parity lists per target -> sorted 16 per (target, split)
  __syncthreads();
#pragma unroll
  for (int o = 0; o < KK; ++o) {
    mbD[tid * KK + o] = bd[o];
    mbI[tid * KK + o] = bi[o];
  }
  __syncthreads();
  if (tid < TT) {
    const float* la = &mbD[(2 * tid) * KK];
    const float* lb = &mbD[(2 * tid + 1) * KK];
    const int* ia = &mbI[(2 * tid) * KK];
    const int* ib = &mbI[(2 * tid + 1) * KK];
    int pa = 0, pb = 0;
    size_t base = ((size_t)(tb + tid) * NSPLIT + split) * KK;
#pragma unroll
    for (int o = 0; o < KK; ++o) {
      float da = la[pa], db = lb[pb];
      int iaa = ia[pa], ibb = ib[pb];
      bool pick = (da < db) || (da == db && iaa < ibb);
      part_d[base + o] = pick ? da : db;
      part_i[base + o] = pick ? iaa : ibb;
      pa += pick ? 1 : 0;
      pb += pick ? 0 : 1;
    }
  }
}

// merge split lists -> approx top-32 candidate indices per target
__global__ void k_knn_merge(const float* __restrict__ part_d, const int* __restrict__ part_i,
                            int* __restrict__ cand) {
  int n = blockIdx.x * 256 + threadIdx.x;
  const float* pd = part_d + (size_t)n * NSPLIT * KK;
  const int* pi = part_i + (size_t)n * NSPLIT * KK;
  int pos[NSPLIT];
#pragma unroll
  for (int l = 0; l < NSPLIT; ++l) pos[l] = 0;
  for (int o = 0; o < MCAND; ++o) {
    float bestd = 3.3e38f;
    int besti = 0x7fffffff;
    int bestl = 0;
#pragma unroll
    for (int l = 0; l < NSPLIT; ++l) {
      if (pos[l] < KK) {
        float dd = pd[l * KK + pos[l]];
        int ii = pi[l * KK + pos[l]];
        if (dd < bestd || (dd == bestd && ii < besti)) { bestd = dd; besti = ii; bestl = l; }
      }
    }
    cand[(size_t)n * MCAND + o] = besti;
#pragma unroll
    for (int l = 0; l < NSPLIT; ++l) pos[l] += (l == bestl) ? 1 : 0;
  }
}

// exact fp32 rerank of 32 candidates -> ordered top-16 (same math/ties as full fp32 scan)
__global__ __launch_bounds__(256) void k_rerank(const float* __restrict__ x,
                                                const float* __restrict__ sq,
                                                const int* __restrict__ cand,
                                                int* __restrict__ knn_src) {
  int tid = threadIdx.x;
  int wave = tid >> 6, lane = tid & 63;
  int t = blockIdx.x * 4 + wave;
  int c = lane & 31, h = lane >> 5;
  int idx = cand[(size_t)t * MCAND + c];
  const float* xt = x + (size_t)t * Dd + h * 64;
  const float* xc = x + (size_t)idx * Dd + h * 64;
  float s = 0.f;
#pragma unroll
  for (int g = 0; g < 16; ++g) {
    float4 a = *(const float4*)&xt[g * 4];
    float4 b = *(const float4*)&xc[g * 4];
    s += a.x * b.x + a.y * b.y + a.z * b.z + a.w * b.w;
  }
  s += __shfl_xor(s, 32);
  float d = fmaf(-2.f, s, sq[t]) + sq[idx];
  int rank = 0;
#pragma unroll
  for (int j = 0; j < 32; ++j) {
    float dj = __shfl(d, j);
    int ij = __shfl(idx, j);
    rank += ((dj < d) || (dj == d && ij < idx)) ? 1 : 0;
  }
  if (lane < 32 && rank < KK) knn_src[t * KK + rank] = idx;
}

// ---------------- static message MLP (bf16x3 MFMA) + grouped scatter-add ----------------
__global__ __launch_bounds__(256, 3) void k_static_msg(
    const float* __restrict__ xs, const float* __restrict__ ea, const int* __restrict__ ei,
    const int* __restrict__ mode_p, const int* __restrict__ perm, const int* __restrict__ dstS,
    const uint4* __restrict__ W1p, const float* __restrict__ b1,
    const uint4* __restrict__ W2p, const float* __restrict__ b2, float* __restrict__ agg) {
  __shared__ __align__(16) ushort smH[32 * 520];
  __shared__ int dstLoc[32];
  int tid = threadIdx.x;
  int wave = tid >> 6, lane = tid & 63;
  int pb = blockIdx.x * 32;
  int mode = *mode_p;
  int r = tid & 31, q8 = tid >> 5;
  int p = pb + r;
  int e = perm[p];
  int ds = dstS[p];
  int sr = ld_src(ei, e, mode);
  if (q8 == 0) dstLoc[r] = ds;
  const float* eap = ea + (size_t)e * DEe;
  const float* xsp = xs + (size_t)sr * Dd;
  const float* xdp = xs + (size_t)ds * Dd;
#pragma unroll
  for (int it = 0; it < 6; ++it) {
    int f = q8 * 24 + it * 4;
    float4 v;
    if (f < 64) {
      v = *(const float4*)&eap[f];
    } else {
      float4 a = *(const float4*)&xsp[f - 64];
      float4 b = *(const float4*)&xdp[f - 64];
      v = make_float4(a.x - b.x, a.y - b.y, a.z - b.z, a.w - b.w);
    }
    uint2 hi, lo;
    cvt_hilo(v, &hi, &lo);
    *(uint2*)&smH[r * 392 + f] = hi;
    *(uint2*)&smH[r * 392 + 192 + f] = lo;
  }
  __syncthreads();
  floatx4 C1[2][4];
  mfma3<6, 4>(smH, 392, W1p + (size_t)wave * 4 * 12 * 64, lane, C1);
  __syncthreads();
  {
    int q = lane >> 4, n15 = lane & 15;
#pragma unroll
    for (int hm = 0; hm < 2; ++hm)
#pragma unroll
      for (int nt = 0; nt < 4; ++nt) {
        int n = wave * 64 + nt * 16 + n15;
        float bv = b1[n];
#pragma unroll
        for (int rr = 0; rr < 4; ++rr) {
          int m = hm * 16 + q * 4 + rr;
          float h = fmaxf(C1[hm][nt][rr] + bv, 0.f);
          ushort hh = f2bf(h);
          smH[m * 520 + n] = hh;
          smH[m * 520 + 256 + n] = f2bf(h - bf2f(hh));
        }
      }
  }
  __syncthreads();
  floatx4 C2[2][2];
  mfma3<8, 2>(smH, 520, W2p + (size_t)wave * 2 * 16 * 64, lane, C2);
  __syncthreads();
  float* smM = (float*)smH;
  {
    int q = lane >> 4, n15 = lane & 15;
#pragma unroll
    for (int hm = 0; hm < 2; ++hm)
#pragma unroll
      for (int nt = 0; nt < 2; ++nt) {
        int n = wave * 32 + nt * 16 + n15;
        float bv = b2[n];
#pragma unroll
        for (int rr = 0; rr < 4; ++rr) {
          int m = hm * 16 + q * 4 + rr;
          smM[m * 132 + n] = fmaxf(C2[hm][nt][rr] + bv, 0.f);
        }
      }
  }
  __syncthreads();
  int col = tid & 127, half = tid >> 7;
  int r0 = half * 16;
  float run = smM[r0 * 132 + col];
  int prevd = dstLoc[r0];
  for (int rr = 1; rr < 16; ++rr) {
    int row = r0 + rr;
    int dd2 = dstLoc[row];
    float v = smM[row * 132 + col];
    if (dd2 != prevd) {
      atomicAdd(&agg[(size_t)prevd * Dd + col], run);
      run = v;
      prevd = dd2;
    } else {
      run += v;
    }
  }
  atomicAdd(&agg[(size_t)prevd * Dd + col], run);
}

// ---------------- dynamic (kNN) message MLP (bf16x3 MFMA), atomic-free ----------------
__global__ __launch_bounds__(256, 3) void k_dyn_msg(
    const float* __restrict__ xd, const int* __restrict__ knn, const uint4* __restrict__ W1p,
    const float* __restrict__ b1, const uint4* __restrict__ W2p, const float* __restrict__ b2,
    float* __restrict__ agg) {
  __shared__ __align__(16) ushort smH[32 * 520];
  int tid = threadIdx.x;
  int wave = tid >> 6, lane = tid & 63;
  int nb2 = blockIdx.x * 2;
  int r = tid & 31, q8 = tid >> 5;
  int tgt = nb2 + (r >> 4);
  int nj = knn[tgt * KK + (r & 15)];
  const float* xip = xd + (size_t)tgt * Dd;
  const float* xjp = xd + (size_t)nj * Dd;
#pragma unroll
  for (int it = 0; it < 8; ++it) {
    int f = q8 * 32 + it * 4;
    float4 v;
    if (f < 128) {
      v = *(const float4*)&xip[f];
    } else {
      float4 a = *(const float4*)&xjp[f - 128];
      float4 b = *(const float4*)&xip[f - 128];
      v = make_float4(a.x - b.x, a.y - b.y, a.z - b.z, a.w - b.w);
    }
    uint2 hi, lo;
    cvt_hilo(v, &hi, &lo);
    *(uint2*)&smH[r * 520 + f] = hi;
    *(uint2*)&smH[r * 520 + 256 + f] = lo;
  }
  __syncthreads();
  floatx4 C1[2][4];
  mfma3<8, 4>(smH, 520, W1p + (size_t)wave * 4 * 16 * 64, lane, C1);
  __syncthreads();
  {
    int q = lane >> 4, n15 = lane & 15;
#pragma unroll
    for (int hm = 0; hm < 2; ++hm)
#pragma unroll
      for (int nt = 0; nt < 4; ++nt) {
        int n = wave * 64 + nt * 16 + n15;
        float bv = b1[n];
#pragma unroll
        for (int rr = 0; rr < 4; ++rr) {
          int m = hm * 16 + q * 4 + rr;
          float h = fmaxf(C1[hm][nt][rr] + bv, 0.f);
          ushort hh = f2bf(h);
          smH[m * 520 + n] = hh;
          smH[m * 520 + 256 + n] = f2bf(h - bf2f(hh));
        }
      }
  }
  __syncthreads();
  floatx4 C2[2][2];
  mfma3<8, 2>(smH, 520, W2p + (size_t)wave * 2 * 16 * 64, lane, C2);
  int q = lane >> 4, n15 = lane & 15;
#pragma unroll
  for (int hm = 0; hm < 2; ++hm)
#pragma unroll
    for (int nt = 0; nt < 2; ++nt) {
      int n = wave * 32 + nt * 16 + n15;
      float bv = b2[n];
      float s = 0.f;
#pragma unroll
      for (int rr = 0; rr < 4; ++rr) s += fmaxf(C2[hm][nt][rr] + bv, 0.f);
      s += __shfl_xor(s, 16);
      s += __shfl_xor(s, 32);
      if (q == 0) agg[(size_t)(nb2 + hm) * Dd + n] = s;
    }
}

// ---------------- fp32 fused 2-layer MLP core (node update / fuse) ----------------
__device__ __forceinline__ void mlp_l1(int tid, int indim, const float* __restrict__ W1,
                                       const float* __restrict__ b1, float* smA, float* smB) {
  int rg = tid >> 5, cg = tid & 31;
  float acc[32];
#pragma unroll
  for (int i = 0; i < 32; ++i) acc[i] = 0.f;
  for (int kc = 0; kc < indim / 8; ++kc) {
    const float* W1g = W1 + (size_t)kc * 8 * Hh;
    *(float4*)&smB[tid * 4] = *(const float4*)&W1g[tid * 4];
    *(float4*)&smB[1024 + tid * 4] = *(const float4*)&W1g[1024 + tid * 4];
    __syncthreads();
#pragma unroll
    for (int k = 0; k < 8; ++k) {
      int kk = kc * 8 + k;
      float4 a0 = *(const float4*)&smA[kk * 32 + rg * 4];
      float4 b0 = *(const float4*)&smB[k * Hh + cg * 8];
      float4 b1v = *(const float4*)&smB[k * Hh + cg * 8 + 4];
      float av[4] = {a0.x, a0.y, a0.z, a0.w};
      float bv[8] = {b0.x, b0.y, b0.z, b0.w, b1v.x, b1v.y, b1v.z, b1v.w};
#pragma unroll
      for (int rr = 0; rr < 4; ++rr)
#pragma unroll
        for (int cc = 0; cc < 8; ++cc) acc[rr * 8 + cc] += av[rr] * bv[cc];
    }
    __syncthreads();
  }
  float4 bb0 = *(const float4*)&b1[cg * 8];
  float4 bb1 = *(const float4*)&b1[cg * 8 + 4];
  float bs[8] = {bb0.x, bb0.y, bb0.z, bb0.w, bb1.x, bb1.y, bb1.z, bb1.w};
#pragma unroll
  for (int rr = 0; rr < 4; ++rr) {
    int row = rg * 4 + rr;
    float4 h0, h1;
    h0.x = fmaxf(acc[rr * 8 + 0] + bs[0], 0.f);
    h0.y = fmaxf(acc[rr * 8 + 1] + bs[1], 0.f);
    h0.z = fmaxf(acc[rr * 8 + 2] + bs[2], 0.f);
    h0.w = fmaxf(acc[rr * 8 + 3] + bs[3], 0.f);
    h1.x = fmaxf(acc[rr * 8 + 4] + bs[4], 0.f);
    h1.y = fmaxf(acc[rr * 8 + 5] + bs[5], 0.f);
    h1.z = fmaxf(acc[rr * 8 + 6] + bs[6], 0.f);
    h1.w = fmaxf(acc[rr * 8 + 7] + bs[7], 0.f);
    *(float4*)&smA[row * 260 + cg * 8] = h0;
    *(float4*)&smA[row * 260 + cg * 8 + 4] = h1;
  }
  __syncthreads();
}

__device__ __forceinline__ void mlp_l2(int tid, const float* __restrict__ W2,
                                       const float* smA, float* smB, float acc2[16]) {
  int rg2 = tid >> 5, cg2 = tid & 31;
#pragma unroll
  for (int i = 0; i < 16; ++i) acc2[i] = 0.f;
  for (int kc = 0; kc < Hh / 16; ++kc) {
    const float* W2g = W2 + (size_t)kc * 16 * Dd;
    *(float4*)&smB[tid * 4] = *(const float4*)&W2g[tid * 4];
    *(float4*)&smB[1024 + tid * 4] = *(const float4*)&W2g[1024 + tid * 4];
    __syncthreads();
#pragma unroll
    for (int k = 0; k < 16; ++k) {
      int kk = kc * 16 + k;
      float4 b0 = *(const float4*)&smB[k * Dd + cg2 * 4];
#pragma unroll
      for (int rr = 0; rr < 4; ++rr) {
        float a = smA[(rg2 * 4 + rr) * 260 + kk];
        acc2[rr * 4 + 0] += a * b0.x;
        acc2[rr * 4 + 1] += a * b0.y;
        acc2[rr * 4 + 2] += a * b0.z;
        acc2[rr * 4 + 3] += a * b0.w;
      }
    }
    __syncthreads();
  }
}

__global__ __launch_bounds__(256, 3) void k_node_mlp2(
    const float* __restrict__ in1, const float* __restrict__ in2, int indim,
    const float* __restrict__ W1, const float* __restrict__ b1, const float* __restrict__ W2,
    const float* __restrict__ b2, float* __restrict__ out) {
  __shared__ float smA[32 * 260];
  __shared__ float smB[2048];
  int tid = threadIdx.x;
  int nb = blockIdx.x * 32;
  int r = tid & 31, q = tid >> 5;
  for (int pass = 0; pass < indim / 32; ++pass) {
    int k0 = pass * 32 + q * 4;
    float4 v;
    if (k0 < Dd)
      v = *(const float4*)&in1[(size_t)(nb + r) * Dd + k0];
    else
      v = *(const float4*)&in2[(size_t)(nb + r) * Dd + (k0 - Dd)];
    smA[(k0 + 0) * 32 + r] = v.x;
    smA[(k0 + 1) * 32 + r] = v.y;
    smA[(k0 + 2) * 32 + r] = v.z;
    smA[(k0 + 3) * 32 + r] = v.w;
  }
  __syncthreads();
  mlp_l1(tid, indim, W1, b1, smA, smB);
  float acc2[16];
  mlp_l2(tid, W2, smA, smB, acc2);
  int rg2 = tid >> 5, cg2 = tid & 31;
  float4 ob = *(const float4*)&b2[cg2 * 4];
#pragma unroll
  for (int rr = 0; rr < 4; ++rr) {
    float4 o;
    o.x = fmaxf(acc2[rr * 4 + 0] + ob.x, 0.f);
    o.y = fmaxf(acc2[rr * 4 + 1] + ob.y, 0.f);
    o.z = fmaxf(acc2[rr * 4 + 2] + ob.z, 0.f);
    o.w = fmaxf(acc2[rr * 4 + 3] + ob.w, 0.f);
    *(float4*)&out[(size_t)(nb + rg2 * 4 + rr) * Dd + cg2 * 4] = o;
  }
}

__global__ __launch_bounds__(256) void k_refine(const float* __restrict__ ein,
                                                const float* __restrict__ rW,
                                                const float* __restrict__ rb,
                                                float* __restrict__ eout) {
  __shared__ float lea[16 * 64];
  __shared__ float ldsW[64 * 64];
  int tid = threadIdx.x;
  int eb = blockIdx.x * 16;
  *(float4*)&lea[tid * 4] = *(const float4*)&ein[(size_t)eb * DEe + tid * 4];
#pragma unroll
  for (int m = 0; m < 4; ++m) {
    int i4 = tid + m * 256;
    *(float4*)&ldsW[i4 * 4] = *(const float4*)&rW[i4 * 4];
  }
  __syncthreads();
  int j = tid & 63, eg = tid >> 6;
  float bias = rb[j];
  float acc0 = 0.f, acc1 = 0.f, acc2 = 0.f, acc3 = 0.f;
#pragma unroll 8
  for (int k = 0; k < 64; ++k) {
    float w = ldsW[k * 64 + j];
    acc0 += lea[(eg + 0) * 64 + k] * w;
    acc1 += lea[(eg + 4) * 64 + k] * w;
    acc2 += lea[(eg + 8) * 64 + k] * w;
    acc3 += lea[(eg + 12) * 64 + k] * w;
  }
  eout[(size_t)(eb + eg + 0) * DEe + j] = fmaxf(acc0 + bias, 0.f);
  eout[(size_t)(eb + eg + 4) * DEe + j] = fmaxf(acc1 + bias, 0.f);
  eout[(size_t)(eb + eg + 8) * DEe + j] = fmaxf(acc2 + bias, 0.f);
  eout[(size_t)(eb + eg + 12) * DEe + j] = fmaxf(acc3 + bias, 0.f);
}

extern "C" void kernel_launch(void* const* d_in, const int* in_sizes, int n_in, void* d_out,
                              int out_size, void* d_ws, size_t ws_size, hipStream_t stream) {
  (void)in_sizes; (void)n_in; (void)out_size; (void)ws_size;
  const float* x = (const float*)d_in[0];
  const float* edge_attr = (const float*)d_in[1];
  const float* sW1 = (const float*)d_in[2];
  const float* sb1 = (const float*)d_in[3];
  const float* sW2 = (const float*)d_in[4];
  const float* sb2 = (const float*)d_in[5];
  const float* uW1 = (const float*)d_in[6];
  const float* ub1 = (const float*)d_in[7];
  const float* uW2 = (const float*)d_in[8];
  const float* ub2 = (const float*)d_in[9];
  const float* rW = (const float*)d_in[10];
  const float* rb = (const float*)d_in[11];
  const float* dW1 = (const float*)d_in[12];
  const float* db1 = (const float*)d_in[13];
  const float* dW2 = (const float*)d_in[14];
  const float* db2 = (const float*)d_in[15];
  const float* dUW1 = (const float*)d_in[16];
  const float* dUb1 = (const float*)d_in[17];
  const float* dUW2 = (const float*)d_in[18];
  const float* dUb2 = (const float*)d_in[19];
  const float* fW1 = (const float*)d_in[20];
  const float* fb1 = (const float*)d_in[21];
  const float* fW2 = (const float*)d_in[22];
  const float* fb2 = (const float*)d_in[23];
  const int* ei = (const int*)d_in[24];
  float* out = (float*)d_out;

  float* wsf = (float*)d_ws;
  size_t off = 0;
  float* ea_ws = wsf + off; off += (size_t)Ee * DEe;
  float* xs_ws = wsf + off; off += (size_t)Nn * Dd;
  float* xd_ws = wsf + off; off += (size_t)Nn * Dd;
  float* agg = wsf + off;   off += (size_t)Nn * Dd;
  float* sq = wsf + off;    off += Nn;
  int* knn_src = (int*)(wsf + off); off += (size_t)Nn * KK;
  int* hist = (int*)(wsf + off);   off += Nn;
  int* cursor = (int*)(wsf + off); off += Nn;
  int* perm = (int*)(wsf + off);   off += Ee;
  int* dstS = (int*)(wsf + off);   off += Ee;
  int* modep = (int*)(wsf + off);  off += 1;
  off = (off + 3) & ~(size_t)3;  // 16B align for uint4
  uint4* wpk = (uint4*)(wsf + off); off += (size_t)110592 * 4;
  // kNN scratch overlaps ea_ws (edge_attr refinement dead before dynamic branch)
  float* part_d = ea_ws;
  int* part_i = (int*)(ea_ws + (size_t)Nn * NSPLIT * KK);
  int* cand = (int*)(ea_ws + 2 * (size_t)Nn * NSPLIT * KK);

  // edge_index probe + counting sort by dst
  k_detect<<<1, 64, 0, stream>>>(ei, modep);
  hipMemsetAsync(hist, 0, Nn * sizeof(int), stream);
  k_hist<<<Ee / 256, 256, 0, stream>>>(ei, modep, hist);
  k_scan<<<1, 256, 0, stream>>>(hist, cursor);
  k_scatter<<<Ee / 256, 256, 0, stream>>>(ei, modep, cursor, perm, dstS);

  // repack all msg-MLP weights into bf16 hi/lo MFMA-B layout
  k_repack<<<432, 256, 0, stream>>>(sW1, sW2, dW1, dW2, wpk);

  // ---- static branch: 3 convs + 2 refiners ----
  const float* xs_cur = x;
  const float* ea_cur = edge_attr;
  for (int i = 0; i < 3; ++i) {
    hipMemsetAsync(agg, 0, (size_t)Nn * Dd * sizeof(float), stream);
    k_static_msg<<<Ee / 32, 256, 0, stream>>>(
        xs_cur, ea_cur, ei, modep, perm, dstS, wpk + (size_t)i * 12288,
        sb1 + (size_t)i * Hh, wpk + 36864 + (size_t)i * 8192, sb2 + (size_t)i * Dd, agg);
    k_node_mlp2<<<Nn / 32, 256, 0, stream>>>(
        agg, (const float*)nullptr, Dd, uW1 + (size_t)i * Dd * Hh, ub1 + (size_t)i * Hh,
        uW2 + (size_t)i * Hh * Dd, ub2 + (size_t)i * Dd, xs_ws);
    xs_cur = xs_ws;
    if (i < 2) {
      k_refine<<<Ee / 16, 256, 0, stream>>>(ea_cur, rW + (size_t)i * DEe * DEe,
                                            rb + (size_t)i * DEe, ea_ws);
      ea_cur = ea_ws;
    }
  }

  // ---- dynamic branch: 2 kNN convs (MFMA prefilter -> merge32 -> exact rerank) ----
  const float* xd_cur = x;
  for (int i = 0; i < 2; ++i) {
    k_sq<<<Nn / 256, 256, 0, stream>>>(xd_cur, sq);
    k_knn_part<<<(Nn / TT) * NSPLIT, 256, 0, stream>>>(xd_cur, sq, part_d, part_i);
    k_knn_merge<<<Nn / 256, 256, 0, stream>>>(part_d, part_i, cand);
    k_rerank<<<Nn / 4, 256, 0, stream>>>(xd_cur, sq, cand, knn_src);
    k_dyn_msg<<<Nn / 2, 256, 0, stream>>>(
        xd_cur, knn_src, wpk + 61440 + (size_t)i * 16384, db1 + (size_t)i * Hh,
        wpk + 94208 + (size_t)i * 8192, db2 + (size_t)i * Dd, agg);
    k_node_mlp2<<<Nn / 32, 256, 0, stream>>>(
        agg, (const float*)nullptr, Dd, dUW1 + (size_t)i * Dd * Hh, dUb1 + (size_t)i * Hh,
        dUW2 + (size_t)i * Hh * Dd, dUb2 + (size_t)i * Dd, xd_ws);
    xd_cur = xd_ws;
  }

  // ---- fuse MLP ----
  k_node_mlp2<<<Nn / 32, 256, 0, stream>>>(xs_ws, xd_ws, 2 * Dd, fW1, fb1, fW2, fb2, out);
}